// Round 11
// baseline (960.144 us; speedup 1.0000x reference)
//
#include <hip/hip_runtime.h>

// TransformerXL forward, MI355X. Round 11: GEMM K-loop -> 2-phase double
// buffer (BK=32, single barrier per step AFTER MFMA; stage latency hidden
// under compute; same LDS footprint -> 4 blocks/CU kept). Attn r7 unchanged.
// L=256, KLEN=512, B=32, E=512, H=8, D=64, FF=2048, NL=4.

typedef __attribute__((ext_vector_type(8))) short bf8_t;    // 8 bf16 in 4 VGPRs
typedef __attribute__((ext_vector_type(4))) float f4_t;
typedef __attribute__((ext_vector_type(16))) float fx16;    // 32x32 accum

__device__ __forceinline__ ushort f2bf(float f) {           // RNE f32->bf16
    uint u = __float_as_uint(f);
    u += 0x7FFFu + ((u >> 16) & 1u);
    return (ushort)(u >> 16);
}
__device__ __forceinline__ float b2f(ushort h) {
    return __uint_as_float(((uint)h) << 16);
}
__device__ __forceinline__ void gload16(const void* g, void* l) {
    __builtin_amdgcn_global_load_lds((const __attribute__((address_space(1))) void*)g,
                                     (__attribute__((address_space(3))) void*)l, 16, 0, 0);
}

// ---------------- 32x32x16 MFMA core for one BK=32 buffer ------------------
// As/Bs: [128][32] ushort, chunk-swizzled (LDS[row][c] = global[row][c^(row&3)]).
// Wave covers rows rowA0..+63 x cols colB0..+63 as 2x2 of 32x32 frags.
// A/B frag: row = lane&31, k = kk*16 + (lane>>5)*8 + e.
__device__ __forceinline__ void mma32_k32(const ushort* __restrict__ As,
                                          const ushort* __restrict__ Bs,
                                          int rowA0, int colB0,
                                          int l31, int hi, fx16 acc[2][2])
{
#pragma unroll
    for (int kk = 0; kk < 2; ++kk) {
        bf8_t av[2], bv[2];
#pragma unroll
        for (int i = 0; i < 2; ++i) {
            const int row = rowA0 + i * 32 + l31;
            const int ch = (kk * 2 + hi) ^ (row & 3);
            av[i] = *(const bf8_t*)(As + row * 32 + ch * 8);
        }
#pragma unroll
        for (int j = 0; j < 2; ++j) {
            const int row = colB0 + j * 32 + l31;
            const int ch = (kk * 2 + hi) ^ (row & 3);
            bv[j] = *(const bf8_t*)(Bs + row * 32 + ch * 8);
        }
#pragma unroll
        for (int i = 0; i < 2; ++i)
#pragma unroll
            for (int j = 0; j < 2; ++j)
                acc[i][j] = __builtin_amdgcn_mfma_f32_32x32x16_bf16(av[i], bv[j], acc[i][j], 0, 0, 0);
    }
}

// ------------------------------------------------------------ MFMA GEMM bf16
// C[M,N] = A[M,K] @ Bt[N,K]^T (+bias)(+relu). 128x128 tile, BK=32 dbuf,
// 256 thr. One barrier per K-step, placed after the MFMA cluster.
template<bool BIAS, bool RELU, bool OUTBF>
__global__ __launch_bounds__(256)
void gemm_bf(const ushort* __restrict__ A, int lda,
             const ushort* __restrict__ Bt, int ldb,
             const float* __restrict__ bias,
             void* __restrict__ Cp, int ldc,
             int M, int N, int K)
{
    __shared__ __align__(16) ushort sh[17408];   // staging 32KB dbuf / epi [128][136]
    ushort* A0 = sh;             // [128][32] each, chunk-swizzled
    ushort* A1 = sh + 4096;
    ushort* B0 = sh + 8192;
    ushort* B1 = sh + 12288;
    const int t = threadIdx.x;
    const int w = t >> 6, lane = t & 63;
    const int wr = w >> 1, wc = w & 1;
    const int l31 = lane & 31, hi = lane >> 5;
    const int m0 = blockIdx.y * 128, n0 = blockIdx.x * 128;

    // staging: thread t covers rows srow, srow+64; chunk (t&3), pre-swizzled src
    const int srow = t >> 2;
    const int gch = (t & 3) ^ (srow & 3);
    const ushort* Ag = A + (size_t)(m0 + srow) * lda + gch * 8;
    const ushort* Bg = Bt + (size_t)(n0 + srow) * ldb + gch * 8;
    ushort* dA0 = A0 + w * 512;  ushort* dA1 = A1 + w * 512;
    ushort* dB0 = B0 + w * 512;  ushort* dB1 = B1 + w * 512;

    fx16 acc[2][2];
#pragma unroll
    for (int i = 0; i < 2; ++i)
#pragma unroll
        for (int j = 0; j < 2; ++j)
#pragma unroll
            for (int r = 0; r < 16; ++r) acc[i][j][r] = 0.f;

    // prologue: stage k=0 into buf0
    gload16(Ag,            dA0);
    gload16(Ag + 64 * lda, dA0 + 2048);
    gload16(Bg,            dB0);
    gload16(Bg + 64 * ldb, dB0 + 2048);
    __syncthreads();

    for (int k0 = 0; k0 < K; k0 += 32) {
        const bool odd = (k0 & 32) != 0;
        const ushort* Ac = odd ? A1 : A0;
        const ushort* Bc = odd ? B1 : B0;
        if (k0 + 32 < K) {               // stage next tile into other buffer
            const ushort* Agn = Ag + k0 + 32;
            const ushort* Bgn = Bg + k0 + 32;
            gload16(Agn,            odd ? dA0 : dA1);
            gload16(Agn + 64 * lda, (odd ? dA0 : dA1) + 2048);
            gload16(Bgn,            odd ? dB0 : dB1);
            gload16(Bgn + 64 * ldb, (odd ? dB0 : dB1) + 2048);
        }
        mma32_k32(Ac, Bc, wr * 64, wc * 64, l31, hi, acc);
        __syncthreads();                 // drain (stage had MFMA phase to land)
    }
    const int crow0 = wr * 64, ccol0 = wc * 64;
    if (OUTBF) {
        ushort* Cs = sh;   // [128][136]
#pragma unroll
        for (int i = 0; i < 2; ++i)
#pragma unroll
            for (int j = 0; j < 2; ++j) {
                const int colb = ccol0 + j * 32 + l31;
                float bb = BIAS ? bias[n0 + colb] : 0.f;
                fx16 v = acc[i][j];
#pragma unroll
                for (int r = 0; r < 16; ++r) {
                    float o = v[r] + bb;
                    if (RELU) o = fmaxf(o, 0.f);
                    const int rw = crow0 + i * 32 + (r & 3) + 8 * (r >> 2) + 4 * hi;
                    Cs[rw * 136 + colb] = f2bf(o);
                }
            }
        __syncthreads();
        const int orow = t >> 1, oc0 = (t & 1) * 64;
        ushort* dst = (ushort*)Cp + (size_t)(m0 + orow) * ldc + n0 + oc0;
#pragma unroll
        for (int u = 0; u < 8; ++u)
            *(bf8_t*)(dst + u * 8) = *(const bf8_t*)(Cs + orow * 136 + oc0 + u * 8);
    } else {
        float* C = (float*)Cp;
#pragma unroll
        for (int i = 0; i < 2; ++i)
#pragma unroll
            for (int j = 0; j < 2; ++j) {
                const int colb = n0 + ccol0 + j * 32 + l31;
                float bb = BIAS ? bias[colb] : 0.f;
                fx16 v = acc[i][j];
#pragma unroll
                for (int r = 0; r < 16; ++r) {
                    float o = v[r] + bb;
                    if (RELU) o = fmaxf(o, 0.f);
                    const int rw = crow0 + i * 32 + (r & 3) + 8 * (r >> 2) + 4 * hi;
                    C[(size_t)(m0 + rw) * ldc + colb] = o;
                }
            }
    }
}

// ---------------------------------------------- fused q|kv GEMM (col-routed)
// A = curb [8192][512]; Bt = wqkvT_l [1536][512]. Cols 0..511 -> qb [8192][512];
// cols 512..1535 -> kvb rows 8192.. [.][1024]. grid (12,64), 3 blocks/CU.
__global__ __launch_bounds__(256)
void gemm_qkv(const ushort* __restrict__ A, const ushort* __restrict__ Bt,
              ushort* __restrict__ qout, ushort* __restrict__ kvout)
{
    __shared__ __align__(16) ushort sh[17408];
    ushort* A0 = sh;
    ushort* A1 = sh + 4096;
    ushort* B0 = sh + 8192;
    ushort* B1 = sh + 12288;
    const int t = threadIdx.x;
    const int w = t >> 6, lane = t & 63;
    const int wr = w >> 1, wc = w & 1;
    const int l31 = lane & 31, hi = lane >> 5;
    const int m0 = blockIdx.y * 128, n0 = blockIdx.x * 128;

    const int srow = t >> 2;
    const int gch = (t & 3) ^ (srow & 3);
    const ushort* Ag = A + (size_t)(m0 + srow) * 512 + gch * 8;
    const ushort* Bg = Bt + (size_t)(n0 + srow) * 512 + gch * 8;
    ushort* dA0 = A0 + w * 512;  ushort* dA1 = A1 + w * 512;
    ushort* dB0 = B0 + w * 512;  ushort* dB1 = B1 + w * 512;

    fx16 acc[2][2];
#pragma unroll
    for (int i = 0; i < 2; ++i)
#pragma unroll
        for (int j = 0; j < 2; ++j)
#pragma unroll
            for (int r = 0; r < 16; ++r) acc[i][j][r] = 0.f;

    gload16(Ag,            dA0);
    gload16(Ag + 64 * 512, dA0 + 2048);
    gload16(Bg,            dB0);
    gload16(Bg + 64 * 512, dB0 + 2048);
    __syncthreads();

    for (int k0 = 0; k0 < 512; k0 += 32) {
        const bool odd = (k0 & 32) != 0;
        const ushort* Ac = odd ? A1 : A0;
        const ushort* Bc = odd ? B1 : B0;
        if (k0 + 32 < 512) {
            const ushort* Agn = Ag + k0 + 32;
            const ushort* Bgn = Bg + k0 + 32;
            gload16(Agn,            odd ? dA0 : dA1);
            gload16(Agn + 64 * 512, (odd ? dA0 : dA1) + 2048);
            gload16(Bgn,            odd ? dB0 : dB1);
            gload16(Bgn + 64 * 512, (odd ? dB0 : dB1) + 2048);
        }
        mma32_k32(Ac, Bc, wr * 64, wc * 64, l31, hi, acc);
        __syncthreads();
    }
    const int crow0 = wr * 64, ccol0 = wc * 64;
    ushort* Cs = sh;   // [128][136]
#pragma unroll
    for (int i = 0; i < 2; ++i)
#pragma unroll
        for (int j = 0; j < 2; ++j) {
            const int colb = ccol0 + j * 32 + l31;
            fx16 v = acc[i][j];
#pragma unroll
            for (int r = 0; r < 16; ++r) {
                const int rw = crow0 + i * 32 + (r & 3) + 8 * (r >> 2) + 4 * hi;
                Cs[rw * 136 + colb] = f2bf(v[r]);
            }
        }
    __syncthreads();
    ushort* base; size_t ldc2;
    if (n0 < 512) { base = qout + n0; ldc2 = 512; }
    else          { base = kvout + (size_t)8192 * 1024 + (n0 - 512); ldc2 = 1024; }
    const int orow = t >> 1, oc0 = (t & 1) * 64;
    ushort* dst = base + (size_t)(m0 + orow) * ldc2 + oc0;
#pragma unroll
    for (int u = 0; u < 8; ++u)
        *(bf8_t*)(dst + u * 8) = *(const bf8_t*)(Cs + orow * 136 + oc0 + u * 8);
}

// ------------------------------------------------ split-K GEMM (f32 partials)
// z = blockIdx.z selects K-half; z=0 -> C0 (+bias), z=1 -> C1. KH = K/2.
template<bool BIAS>
__global__ __launch_bounds__(256)
void gemm_sk(const ushort* __restrict__ A, int lda,
             const ushort* __restrict__ Bt, int ldb,
             const float* __restrict__ bias,
             float* __restrict__ C0, float* __restrict__ C1, int ldc, int KH)
{
    __shared__ __align__(16) ushort sh[16384];
    ushort* A0 = sh;
    ushort* A1 = sh + 4096;
    ushort* B0 = sh + 8192;
    ushort* B1 = sh + 12288;
    const int t = threadIdx.x;
    const int w = t >> 6, lane = t & 63;
    const int wr = w >> 1, wc = w & 1;
    const int l31 = lane & 31, hi = lane >> 5;
    const int m0 = blockIdx.y * 128, n0 = blockIdx.x * 128;
    const int z = blockIdx.z;
    A += (size_t)z * KH; Bt += (size_t)z * KH;
    float* C = z ? C1 : C0;

    const int srow = t >> 2;
    const int gch = (t & 3) ^ (srow & 3);
    const ushort* Ag = A + (size_t)(m0 + srow) * lda + gch * 8;
    const ushort* Bg = Bt + (size_t)(n0 + srow) * ldb + gch * 8;
    ushort* dA0 = A0 + w * 512;  ushort* dA1 = A1 + w * 512;
    ushort* dB0 = B0 + w * 512;  ushort* dB1 = B1 + w * 512;

    fx16 acc[2][2];
#pragma unroll
    for (int i = 0; i < 2; ++i)
#pragma unroll
        for (int j = 0; j < 2; ++j)
#pragma unroll
            for (int r = 0; r < 16; ++r) acc[i][j][r] = 0.f;

    gload16(Ag,            dA0);
    gload16(Ag + 64 * lda, dA0 + 2048);
    gload16(Bg,            dB0);
    gload16(Bg + 64 * ldb, dB0 + 2048);
    __syncthreads();

    for (int k0 = 0; k0 < KH; k0 += 32) {
        const bool odd = (k0 & 32) != 0;
        const ushort* Ac = odd ? A1 : A0;
        const ushort* Bc = odd ? B1 : B0;
        if (k0 + 32 < KH) {
            const ushort* Agn = Ag + k0 + 32;
            const ushort* Bgn = Bg + k0 + 32;
            gload16(Agn,            odd ? dA0 : dA1);
            gload16(Agn + 64 * lda, (odd ? dA0 : dA1) + 2048);
            gload16(Bgn,            odd ? dB0 : dB1);
            gload16(Bgn + 64 * ldb, (odd ? dB0 : dB1) + 2048);
        }
        mma32_k32(Ac, Bc, wr * 64, wc * 64, l31, hi, acc);
        __syncthreads();
    }
    const int crow0 = wr * 64, ccol0 = wc * 64;
#pragma unroll
    for (int i = 0; i < 2; ++i)
#pragma unroll
        for (int j = 0; j < 2; ++j) {
            const int colb = n0 + ccol0 + j * 32 + l31;
            float bb = (BIAS && z == 0) ? bias[colb] : 0.f;
            fx16 v = acc[i][j];
#pragma unroll
            for (int r = 0; r < 16; ++r) {
                const int rw = crow0 + i * 32 + (r & 3) + 8 * (r >> 2) + 4 * hi;
                C[(size_t)(m0 + rw) * ldc + colb] = v[r] + bb;
            }
        }
}

// ---------------------------------------------------------------- LayerNorm
// RMODE: 0 X; 1 X+Rf32; 2 X+Rbf16; 3 X+X2+Rbf16; 4 X+X2+Rf32.
// TROUT: f32 out transposed to [B,L].
template<int RMODE, bool TROUT>
__global__ __launch_bounds__(256)
void ln_k(const float* __restrict__ X, const float* __restrict__ X2,
          const void* __restrict__ Rp,
          const float* __restrict__ g, const float* __restrict__ bt,
          float* __restrict__ Yf, ushort* __restrict__ Yb,
          float eps, int do_relu)
{
    const int row  = blockIdx.x * 4 + (threadIdx.x >> 6);
    const int lane = threadIdx.x & 63;
    const float* xp = X + (size_t)row * 512 + lane * 8;
    float4 x0 = *(const float4*)xp, x1 = *(const float4*)(xp + 4);
    float v[8] = {x0.x, x0.y, x0.z, x0.w, x1.x, x1.y, x1.z, x1.w};
    if (RMODE == 3 || RMODE == 4) {
        const float* p2 = X2 + (size_t)row * 512 + lane * 8;
        float4 a0 = *(const float4*)p2, a1 = *(const float4*)(p2 + 4);
        v[0] += a0.x; v[1] += a0.y; v[2] += a0.z; v[3] += a0.w;
        v[4] += a1.x; v[5] += a1.y; v[6] += a1.z; v[7] += a1.w;
    }
    if (RMODE == 1 || RMODE == 4) {
        const float* rp = (const float*)Rp + (size_t)row * 512 + lane * 8;
        float4 r0 = *(const float4*)rp, r1 = *(const float4*)(rp + 4);
        v[0] += r0.x; v[1] += r0.y; v[2] += r0.z; v[3] += r0.w;
        v[4] += r1.x; v[5] += r1.y; v[6] += r1.z; v[7] += r1.w;
    } else if (RMODE == 2 || RMODE == 3) {
        const ushort* rp = (const ushort*)Rp + (size_t)row * 512 + lane * 8;
        ushort4 r0 = *(const ushort4*)rp, r1 = *(const ushort4*)(rp + 4);
        v[0] += b2f(r0.x); v[1] += b2f(r0.y); v[2] += b2f(r0.z); v[3] += b2f(r0.w);
        v[4] += b2f(r1.x); v[5] += b2f(r1.y); v[6] += b2f(r1.z); v[7] += b2f(r1.w);
    }
    float s = 0.f;
#pragma unroll
    for (int i = 0; i < 8; ++i) s += v[i];
#pragma unroll
    for (int m = 1; m < 64; m <<= 1) s += __shfl_xor(s, m);
    float mean = s * (1.f / 512.f);
    float q = 0.f;
#pragma unroll
    for (int i = 0; i < 8; ++i) { float d = v[i] - mean; q = fmaf(d, d, q); }
#pragma unroll
    for (int m = 1; m < 64; m <<= 1) q += __shfl_xor(q, m);
    float rstd = rsqrtf(q * (1.f / 512.f) + eps);
    float4 g0 = *(const float4*)(g + lane * 8), g1 = *(const float4*)(g + lane * 8 + 4);
    float4 c0 = *(const float4*)(bt + lane * 8), c1 = *(const float4*)(bt + lane * 8 + 4);
    float gv[8] = {g0.x, g0.y, g0.z, g0.w, g1.x, g1.y, g1.z, g1.w};
    float bv[8] = {c0.x, c0.y, c0.z, c0.w, c1.x, c1.y, c1.z, c1.w};
    float o[8];
#pragma unroll
    for (int i = 0; i < 8; ++i) {
        o[i] = (v[i] - mean) * rstd * gv[i] + bv[i];
        if (do_relu) o[i] = fmaxf(o[i], 0.f);
    }
    if (Yf) {
        float* yp;
        if (TROUT) {
            const int bq = row & 31, lq = row >> 5;
            yp = Yf + ((size_t)bq * 256 + lq) * 512 + lane * 8;
        } else {
            yp = Yf + (size_t)row * 512 + lane * 8;
        }
        *(float4*)yp       = make_float4(o[0], o[1], o[2], o[3]);
        *(float4*)(yp + 4) = make_float4(o[4], o[5], o[6], o[7]);
    }
    if (Yb) {
        ushort* yp = Yb + (size_t)row * 512 + lane * 8;
        ushort4 w0, w1;
        w0.x = f2bf(o[0]); w0.y = f2bf(o[1]); w0.z = f2bf(o[2]); w0.w = f2bf(o[3]);
        w1.x = f2bf(o[4]); w1.y = f2bf(o[5]); w1.z = f2bf(o[6]); w1.w = f2bf(o[7]);
        *(ushort4*)yp       = w0;
        *(ushort4*)(yp + 4) = w1;
    }
}

// ------------------------------------------ fused stem double LN (ln2 -> lnf)
__global__ __launch_bounds__(256)
void ln_stem2(const float* __restrict__ X,
              const float* __restrict__ g1, const float* __restrict__ b1,
              const float* __restrict__ g2, const float* __restrict__ b2,
              float* __restrict__ Yf, ushort* __restrict__ Yb)
{
    const int row  = blockIdx.x * 4 + (threadIdx.x >> 6);
    const int lane = threadIdx.x & 63;
    const float* xp = X + (size_t)row * 512 + lane * 8;
    float4 x0 = *(const float4*)xp, x1 = *(const float4*)(xp + 4);
    float v[8] = {x0.x, x0.y, x0.z, x0.w, x1.x, x1.y, x1.z, x1.w};
    float s = 0.f;
#pragma unroll
    for (int i = 0; i < 8; ++i) s += v[i];
#pragma unroll
    for (int m = 1; m < 64; m <<= 1) s += __shfl_xor(s, m);
    float mean = s * (1.f / 512.f);
    float q = 0.f;
#pragma unroll
    for (int i = 0; i < 8; ++i) { float d = v[i] - mean; q = fmaf(d, d, q); }
#pragma unroll
    for (int m = 1; m < 64; m <<= 1) q += __shfl_xor(q, m);
    float rstd = rsqrtf(q * (1.f / 512.f) + 1e-5f);
#pragma unroll
    for (int i = 0; i < 8; ++i)
        v[i] = (v[i] - mean) * rstd * g1[lane * 8 + i] + b1[lane * 8 + i];
    s = 0.f;
#pragma unroll
    for (int i = 0; i < 8; ++i) s += v[i];
#pragma unroll
    for (int m = 1; m < 64; m <<= 1) s += __shfl_xor(s, m);
    mean = s * (1.f / 512.f);
    q = 0.f;
#pragma unroll
    for (int i = 0; i < 8; ++i) { float d = v[i] - mean; q = fmaf(d, d, q); }
#pragma unroll
    for (int m = 1; m < 64; m <<= 1) q += __shfl_xor(q, m);
    rstd = rsqrtf(q * (1.f / 512.f) + 1e-6f);
    float o[8];
#pragma unroll
    for (int i = 0; i < 8; ++i)
        o[i] = (v[i] - mean) * rstd * g2[lane * 8 + i] + b2[lane * 8 + i];
    float* yp = Yf + (size_t)row * 512 + lane * 8;
    *(float4*)yp       = make_float4(o[0], o[1], o[2], o[3]);
    *(float4*)(yp + 4) = make_float4(o[4], o[5], o[6], o[7]);
    ushort* yb = Yb + (size_t)row * 512 + lane * 8;
    ushort4 w0, w1;
    w0.x = f2bf(o[0]); w0.y = f2bf(o[1]); w0.z = f2bf(o[2]); w0.w = f2bf(o[3]);
    w1.x = f2bf(o[4]); w1.y = f2bf(o[5]); w1.z = f2bf(o[6]); w1.w = f2bf(o[7]);
    *(ushort4*)yb       = w0;
    *(ushort4*)(yb + 4) = w1;
}

// ---------------------------------------------- weight transpose+cast f32->bf16
__global__ __launch_bounds__(256)
void wtrans(const float* __restrict__ in, ushort* __restrict__ out, int K, int N)
{
    __shared__ float tl[32][33];
    const size_t bo = (size_t)blockIdx.z * K * N;
    in += bo; out += bo;
    const int k0 = blockIdx.y * 32, n0 = blockIdx.x * 32;
    const int tx = threadIdx.x & 31, ty = threadIdx.x >> 5;
    for (int i = ty; i < 32; i += 8) tl[i][tx] = in[(size_t)(k0 + i) * N + n0 + tx];
    __syncthreads();
    for (int i = ty; i < 32; i += 8) out[(size_t)(n0 + i) * K + k0 + tx] = f2bf(tl[tx][i]);
}

__global__ void convk(const float* __restrict__ in, ushort* __restrict__ out)
{
    int i = (blockIdx.x * 256 + threadIdx.x) * 4;
    float4 v = *(const float4*)(in + i);
    ushort4 o;
    o.x = f2bf(v.x); o.y = f2bf(v.y); o.z = f2bf(v.z); o.w = f2bf(v.w);
    *(ushort4*)(out + i) = o;
}

// ----------------------------------------------------- stem concat [x | act]
__global__ void build_xcat(const float* __restrict__ x, const int* __restrict__ action,
                           const float* __restrict__ act_emb, ushort* __restrict__ xcat)
{
    int idx = blockIdx.x * 256 + threadIdx.x;           // 8192*576
    int n = idx / 576, e = idx - n * 576;
    int l = n >> 5, b = n & 31;
    float v;
    if (e < 512) v = x[((size_t)b * 256 + l) * 512 + e];
    else         v = act_emb[action[b * 32 + (l >> 3)] * 64 + (e - 512)];
    xcat[idx] = f2bf(v);
}

// ------------------------------------------------- sinusoidal pos embedding
__global__ void build_posemb(ushort* __restrict__ pe)
{
    int idx = blockIdx.x * 256 + threadIdx.x;           // 512*512
    int j = idx >> 9, c = idx & 511;
    float pf = (float)(511 - j);
    int i2 = (c < 256) ? c : c - 256;
    float inv = expf(-(float)i2 * 0.03597789207803197f);
    float ang = pf * inv;
    pe[idx] = f2bf((c < 256) ? sinf(ang) : cosf(ang));
}

// --------------------------------------------------- MFMA flash attention
// r7 kernel (proven 66 us): Rs rolling 3-slab LDS band + T14 register
// prefetch of next tile's K/V/R. block = (b*8+h)*2 + ihalf; 8 waves.
__global__ __launch_bounds__(512)
void attn_mfma(const ushort* __restrict__ q,    // [256*32][512]
               const ushort* __restrict__ kv,   // [512*32][1024]  k | v halves
               const ushort* __restrict__ rb,   // [512][512]
               const float* __restrict__ ub, const float* __restrict__ vb,
               ushort* __restrict__ ao)         // [256*32][512]
{
    __shared__ __align__(16) ushort Ks[64][72];     // K tile  [j][d]
    __shared__ __align__(16) ushort Vs[64][72];     // V^T tile [d][j]
    __shared__ __align__(16) ushort Rs[192][72];    // rolling r band (3 slabs)
    __shared__ __align__(16) ushort Ps[8][16][72];  // per-wave P / O bounce
    const int t = threadIdx.x;
    const int wv = t >> 6, lane = t & 63;
    const int lc = lane & 15, lr = lane >> 4;
    const int bh = (int)blockIdx.x >> 1, ihalf = blockIdx.x & 1;
    const int b = bh >> 3, h = bh & 7;
    const int i0 = ihalf << 7;
    const int iw = i0 + wv * 16;

    // q A-fragments with u/v bias folded
    bf8_t au[2], aw[2];
#pragma unroll
    for (int kk = 0; kk < 2; ++kk) {
        const ushort* qp = q + ((size_t)(iw + lc) * 32 + b) * 512 + h * 64 + kk * 32 + lr * 8;
        bf8_t q8 = *(const bf8_t*)qp;
        const float* up = ub + h * 64 + kk * 32 + lr * 8;
        const float* vp = vb + h * 64 + kk * 32 + lr * 8;
#pragma unroll
        for (int e = 0; e < 8; ++e) {
            float qf = b2f((ushort)q8[e]);
            au[kk][e] = (short)f2bf(qf + up[e]);
            aw[kk][e] = (short)f2bf(qf + vp[e]);
        }
    }

    // staging indices
    const int jl = t >> 3, d0 = (t & 7) * 8;
    const int vrow = ((t >> 3) & 7) * 8 + wv;

    f4_t o[4];
#pragma unroll
    for (int d = 0; d < 4; ++d) o[d] = (f4_t){0.f, 0.f, 0.f, 0.f};
    float mrun[4] = {-3.0e38f, -3.0e38f, -3.0e38f, -3.0e38f};
    float lrun[4] = {0.f, 0.f, 0.f, 0.f};

    // ---- prologue: stage tile 0 (K, V^T, all 3 R slabs) ----
    {
        *(bf8_t*)&Ks[jl][d0] = *(const bf8_t*)(kv + ((size_t)jl * 32 + b) * 1024 + h * 64 + d0);
        bf8_t vv = *(const bf8_t*)(kv + ((size_t)vrow * 32 + b) * 1024 + 512 + h * 64 + d0);
#pragma unroll
        for (int e = 0; e < 8; ++e) Vs[d0 + e][vrow] = (ushort)vv[e];
        const int rbase0 = 128 - i0;
#pragma unroll
        for (int p = 0; p < 3; ++p) {
            const int jr = min(rbase0 + p * 64 + jl, 511);
            *(bf8_t*)&Rs[p * 64 + jl][d0] = *(const bf8_t*)(rb + (size_t)jr * 512 + h * 64 + d0);
        }
    }
    __syncthreads();

    const int njt = ihalf ? 8 : 6;
    for (int jt = 0; jt < njt; ++jt) {
        const int j0 = jt << 6;
        // ---- prefetch next tile into registers (overlaps compute below) ----
        bf8_t pk, pv, pr;
        const bool pfq = (jt + 1 < njt);
        if (pfq) {
            const int j0n = j0 + 64;
            pk = *(const bf8_t*)(kv + ((size_t)(j0n + jl) * 32 + b) * 1024 + h * 64 + d0);
            pv = *(const bf8_t*)(kv + ((size_t)(j0n + vrow) * 32 + b) * 1024 + 512 + h * 64 + d0);
            const int jr = min(j0n - i0 + 256 + jl, 511);
            pr = *(const bf8_t*)(rb + (size_t)jr * 512 + h * 64 + d0);
        }
        // ---- compute on tile jt ----
        if (j0 <= iw + 271) {
            f4_t acf[4], bdf[5];
#pragma unroll
            for (int jj = 0; jj < 4; ++jj) acf[jj] = (f4_t){0.f, 0.f, 0.f, 0.f};
#pragma unroll
            for (int fj = 0; fj < 5; ++fj) bdf[fj] = (f4_t){0.f, 0.f, 0.f, 0.f};
#pragma unroll
            for (int jj = 0; jj < 4; ++jj)
#pragma unroll
                for (int kk = 0; kk < 2; ++kk) {
                    bf8_t kf = *(const bf8_t*)&Ks[jj * 16 + lc][kk * 32 + lr * 8];
                    acf[jj] = __builtin_amdgcn_mfma_f32_16x16x32_bf16(au[kk], kf, acf[jj], 0, 0, 0);
                }
            const int rboff = 112 - wv * 16;
#pragma unroll
            for (int fj = 0; fj < 5; ++fj) {
                const int lbase = rboff + fj * 16;
                const int prow = ((jt + (lbase >> 6)) % 3) * 64 + (lbase & 63) + lc;
#pragma unroll
                for (int kk = 0; kk < 2; ++kk) {
                    bf8_t rf = *(const bf8_t*)&Rs[prow][kk * 32 + lr * 8];
                    bdf[fj] = __builtin_amdgcn_mfma_f32_16x16x32_bf16(aw[kk], rf, bdf[fj], 0, 0, 0);
                }
            }
            // ---- rel-shift shuffle + mask + online softmax ----
            float pm[4][4];
            float mt[4] = {-3.0e38f, -3.0e38f, -3.0e38f, -3.0e38f};
            const int jbase = j0 + lc - iw - 256;
#pragma unroll
            for (int rg = 0; rg < 4; ++rg) {
                const int il = lr * 4 + rg;
                const int srcl = (lane & 48) | ((lc + 15 - il) & 15);
                float shf[5];
#pragma unroll
                for (int fj = 0; fj < 5; ++fj) shf[fj] = __shfl(bdf[fj][rg], srcl, 64);
#pragma unroll
                for (int jj = 0; jj < 4; ++jj) {
                    float bd = (lc > il) ? shf[jj + 1] : shf[jj];
                    float s = (acf[jj][rg] + bd) * 0.125f;
                    if (jbase + jj * 16 > il) s = -1e30f;
                    pm[jj][rg] = s;
                    mt[rg] = fmaxf(mt[rg], s);
                }
            }
            float corr[4];
#pragma unroll
            for (int rg = 0; rg < 4; ++rg) {
#pragma unroll
                for (int mm = 1; mm < 16; mm <<= 1)
                    mt[rg] = fmaxf(mt[rg], __shfl_xor(mt[rg], mm, 64));
                float mnew = fmaxf(mrun[rg], mt[rg]);
                corr[rg] = __expf(mrun[rg] - mnew);
                mrun[rg] = mnew;
            }
            float ps4[4] = {0.f, 0.f, 0.f, 0.f};
#pragma unroll
            for (int jj = 0; jj < 4; ++jj)
#pragma unroll
                for (int rg = 0; rg < 4; ++rg) {
                    float p = __expf(pm[jj][rg] - mrun[rg]);
                    ps4[rg] += p;
                    Ps[wv][lr * 4 + rg][jj * 16 + lc] = f2bf(p);
                }
#pragma unroll
            for (int rg = 0; rg < 4; ++rg) {
#pragma unroll
                for (int mm = 1; mm < 16; mm <<= 1)
                    ps4[rg] += __shfl_xor(ps4[rg], mm, 64);
                lrun[rg] = lrun[rg] * corr[rg] + ps4[rg];
            }
            float c0 = __shfl(corr[0], (lc >> 2) << 4, 64);
            float c1 = __shfl(corr[1], (lc >> 2) << 4, 64);
            float c2 = __shfl(corr[2], (lc >> 2) << 4, 64);
            float c3 = __shfl(corr[3], (lc >> 2) << 4, 64);
            float myc = (lc & 2) ? ((lc & 1) ? c3 : c2) : ((lc & 1) ? c1 : c0);
#pragma unroll
            for (int db = 0; db < 4; ++db)
#pragma unroll
                for (int rg = 0; rg < 4; ++rg) o[db][rg] *= myc;
#pragma unroll
            for (int kb = 0; kb < 2; ++kb) {
                bf8_t pf = *(const bf8_t*)&Ps[wv][lc][kb * 32 + lr * 8];
#pragma unroll
                for (int db = 0; db < 4; ++db) {
                    bf8_t vf = *(const bf8_t*)&Vs[db * 16 + lc][kb * 32 + lr * 8];
                    o[db] = __builtin_amdgcn_mfma_f32_16x16x32_bf16(vf, pf, o[db], 0, 0, 0);
                }
            }
        }
        __syncthreads();                 // all waves done reading LDS tile jt
        if (pfq) {                       // write prefetched tile jt+1
            *(bf8_t*)&Ks[jl][d0] = pk;
#pragma unroll
            for (int e = 0; e < 8; ++e) Vs[d0 + e][vrow] = (ushort)pv[e];
            const int phys = (jt % 3) * 64 + jl;     // slab for logical band top
            *(bf8_t*)&Rs[phys][d0] = pr;
        }
        __syncthreads();                 // writes visible before next compute
    }
    // ---- epilogue: scale by 1/l, bounce O^T -> row-major via Ps, store ----
    float i4[4];
#pragma unroll
    for (int rg = 0; rg < 4; ++rg) i4[rg] = 1.f / lrun[rg];
    float s0 = __shfl(i4[0], (lc >> 2) << 4, 64);
    float s1 = __shfl(i4[1], (lc >> 2) << 4, 64);
    float s2 = __shfl(i4[2], (lc >> 2) << 4, 64);
    float s3 = __shfl(i4[3], (lc >> 2) << 4, 64);
    float myi = (lc & 2) ? ((lc & 1) ? s3 : s2) : ((lc & 1) ? s1 : s0);
#pragma unroll
    for (int db = 0; db < 4; ++db)
#pragma unroll
        for (int rg = 0; rg < 4; ++rg)
            Ps[wv][lc][db * 16 + lr * 4 + rg] = f2bf(o[db][rg] * myi);
    const int il2 = lane >> 2, dsg = (lane & 3) << 4;
    bf8_t e0 = *(const bf8_t*)&Ps[wv][il2][dsg];
    bf8_t e1 = *(const bf8_t*)&Ps[wv][il2][dsg + 8];
    ushort* dst = ao + ((size_t)(iw + il2) * 32 + b) * 512 + h * 64 + dsg;
    *(bf8_t*)dst = e0;
    *(bf8_t*)(dst + 8) = e1;
}

// ---------------------------------------------------------------------------
extern "C" void kernel_launch(void* const* d_in, const int* in_sizes, int n_in,
                              void* d_out, int out_size, void* d_ws, size_t ws_size,
                              hipStream_t stream)
{
    const float* x       = (const float*)d_in[0];
    const int*   action  = (const int*)d_in[1];
    const float* mems    = (const float*)d_in[4];
    const float* act_emb = (const float*)d_in[5];
    const float* stem_w1 = (const float*)d_in[6];
    const float* sln1g   = (const float*)d_in[7];
    const float* sln1b   = (const float*)d_in[8];
    const float* stem_w2 = (const float*)d_in[9];
    const float* sln2g   = (const float*)d_in[10];
    const float* sln2b   = (const float*)d_in[11];
    const float* lnfg    = (const float*)d_in[12];
    const float* lnfb    = (const float*)d_in[13];
    const float* ub      = (const float*)d_in[14];
    const float* vb      = (const float*)d_in[15];
    const float* Wqkv    = (const float*)d_in[16];
    const float* Wr      = (const float*)d_in[17];
    const float* Wo      = (const float*)d_in[18];
    const float* ln1g    = (const float*)d_in[19];
    const float* ln1b    = (const float*)d_in[20];
    const float* W1      = (const float*)d_in[21];
    const float* b1      = (const float*)d_in[22];
    const float* W2      = (const float*)d_in[23];
    const float* b2      = (const float*)d_in[24];
    const float* ln2g    = (const float*)d_in[25];
    const float* ln2b    = (const float*)d_in[26];
    float* out = (float*)d_out;

    // ---- workspace layout (bytes) ----
    char* W = (char*)d_ws;
    float*  cur32 = (float*) (W + 0);           // 16 MB residual f32 / FF2 partial
    float*  g32   = (float*) (W + 16777216);    // 16 MB gemm f32 scratch (hosts memsb)
    ushort* curb  = (ushort*)(W + 33554432);    //  8 MB cur bf16
    ushort* h1b   = (ushort*)(W + 41943040);    //  8 MB h1/ao bf16
    ushort* qb    = (ushort*)(W + 50331648);    //  8 MB q bf16 [8192][512]
    ushort* kvb   = (ushort*)(W + 58720256);    // 32 MB kv bf16 [16384][1024]
    ushort* rbuf  = (ushort*)(W + 92274688);    // 512 KB
    ushort* peb   = (ushort*)(W + 92798976);    // 512 KB
    ushort* wts   = (ushort*)(W + 93323264);    // 27 MB transposed bf16 weights
    ushort* xcatb = kvb;                        // stem alias (dead before kv use)
    ushort* ff1b  = kvb;                        // FF1 alias (kv dead post-attn)
    float*  wopart = (float*)kvb;               // Wo split-K partial (post-attn)
    ushort* memsb = (ushort*)g32;               // alias (g32 dead at layer start)
    ushort* w1t    = wts;                       // [512][576]
    ushort* w2t    = wts + 294912;              // [512][512]
    ushort* wqkvT  = wts + 557056;              // [4][1536][512]
    ushort* wrT    = wts + 3702784;             // [4][512][512]
    ushort* woT    = wts + 4751360;             // [4][512][512]
    ushort* w1T    = wts + 5799936;             // [4][2048][512]
    ushort* w2T    = wts + 9994240;             // [4][512][2048]

    dim3 blk(256);
    wtrans<<<dim3(16, 18, 1), blk, 0, stream>>>(stem_w1, w1t, 576, 512);
    wtrans<<<dim3(16, 16, 1), blk, 0, stream>>>(stem_w2, w2t, 512, 512);
    wtrans<<<dim3(48, 16, 4), blk, 0, stream>>>(Wqkv, wqkvT, 512, 1536);
    wtrans<<<dim3(16, 16, 4), blk, 0, stream>>>(Wr, wrT, 512, 512);
    wtrans<<<dim3(16, 16, 4), blk, 0, stream>>>(Wo, woT, 512, 512);
    wtrans<<<dim3(64, 16, 4), blk, 0, stream>>>(W1, w1T, 512, 2048);
    wtrans<<<dim3(16, 64, 4), blk, 0, stream>>>(W2, w2T, 2048, 512);
    build_posemb<<<1024, blk, 0, stream>>>(peb);

    build_xcat<<<18432, blk, 0, stream>>>(x, action, act_emb, xcatb);
    gemm_bf<false, false, false><<<dim3(4, 64), blk, 0, stream>>>(xcatb, 576, w1t, 576, nullptr, g32, 512, 8192, 512, 576);
    ln_k<0, false><<<2048, blk, 0, stream>>>(g32, nullptr, nullptr, sln1g, sln1b, nullptr, curb, 1e-5f, 1);
    gemm_bf<false, false, false><<<dim3(4, 64), blk, 0, stream>>>(curb, 512, w2t, 512, nullptr, g32, 512, 8192, 512, 512);
    ln_stem2<<<2048, blk, 0, stream>>>(g32, sln2g, sln2b, lnfg, lnfb, cur32, curb);

    for (int l = 0; l < 4; ++l) {
        const ushort* wqkvT_l = wqkvT + (size_t)l * 786432;
        convk<<<4096, blk, 0, stream>>>(mems + (size_t)l * 4194304, memsb);
        // fused q | kv(cur) -> qb and kvb rows 8192..
        gemm_qkv<<<dim3(12, 64), blk, 0, stream>>>(curb, wqkvT_l, qb, kvb);
        // kv(mems) -> kvb rows 0..8191
        gemm_bf<false, false, true><<<dim3(8, 64), blk, 0, stream>>>(memsb, 512, wqkvT_l + 262144, 512, nullptr, kvb, 1024, 8192, 1024, 512);
        gemm_bf<false, false, true><<<dim3(4, 4), blk, 0, stream>>>(peb, 512, wrT + (size_t)l * 262144, 512, nullptr, rbuf, 512, 512, 512, 512);
        attn_mfma<<<512, dim3(512), 0, stream>>>(qb, kvb, rbuf, ub, vb, h1b);
        // Wo split-K: z0 -> g32, z1 -> wopart (kvb region, dead post-attn)
        gemm_sk<false><<<dim3(4, 64, 2), blk, 0, stream>>>(h1b, 512, woT + (size_t)l * 262144, 512, nullptr, g32, wopart, 512, 256);
        ln_k<4, false><<<2048, blk, 0, stream>>>(g32, wopart, cur32, ln1g + l * 512, ln1b + l * 512, nullptr, h1b, 1e-5f, 0);
        gemm_bf<true, true, true><<<dim3(16, 64), blk, 0, stream>>>(h1b, 512, w1T + (size_t)l * 1048576, 512, b1 + l * 2048, ff1b, 2048, 8192, 2048, 512);
        // FF2 split-K: z0 -> g32 (+bias), z1 -> cur32 (residual dead after ln1)
        gemm_sk<true><<<dim3(4, 64, 2), blk, 0, stream>>>(ff1b, 2048, w2T + (size_t)l * 1048576, 2048, b2 + l * 512, g32, cur32, 512, 1024);
        if (l == 3)
            ln_k<3, true><<<2048, blk, 0, stream>>>(g32, cur32, h1b, ln2g + l * 512, ln2b + l * 512, out, nullptr, 1e-5f, 0);
        else
            ln_k<3, false><<<2048, blk, 0, stream>>>(g32, cur32, h1b, ln2g + l * 512, ln2b + l * 512, cur32, curb, 1e-5f, 0);
    }
}

// Round 12
// 879.878 us; speedup vs baseline: 1.0912x; 1.0912x over previous
//
#include <hip/hip_runtime.h>

// TransformerXL forward, MI355X. Round 12: r10 GEMM restored (BK=64 single
// buffer — r11 dbuf regressed per m99/m131); batched pre-loop Wr GEMM
// (gemm_r4, was 4 tiny latency-bound dispatches); T5 setprio in attn MFMA.
// L=256, KLEN=512, B=32, E=512, H=8, D=64, FF=2048, NL=4.

typedef __attribute__((ext_vector_type(8))) short bf8_t;    // 8 bf16 in 4 VGPRs
typedef __attribute__((ext_vector_type(4))) float f4_t;
typedef __attribute__((ext_vector_type(16))) float fx16;    // 32x32 accum

__device__ __forceinline__ ushort f2bf(float f) {           // RNE f32->bf16
    uint u = __float_as_uint(f);
    u += 0x7FFFu + ((u >> 16) & 1u);
    return (ushort)(u >> 16);
}
__device__ __forceinline__ float b2f(ushort h) {
    return __uint_as_float(((uint)h) << 16);
}
__device__ __forceinline__ void gload16(const void* g, void* l) {
    __builtin_amdgcn_global_load_lds((const __attribute__((address_space(1))) void*)g,
                                     (__attribute__((address_space(3))) void*)l, 16, 0, 0);
}

// ---------------- shared 32x32x16 MFMA core for one BK=64 step -------------
// As/Bs: [128][64] ushort, chunk-swizzled (LDS[row][c] = global[row][c^(row&7)]).
// Wave covers rows rowA0..+63 x cols colB0..+63 as 2x2 of 32x32 frags.
// A/B frag: row = lane&31, k = (lane>>5)*8 + e. Global k-chunk = kk*2 + hi.
__device__ __forceinline__ void mma32_step(const ushort* __restrict__ As,
                                           const ushort* __restrict__ Bs,
                                           int rowA0, int colB0,
                                           int l31, int hi, fx16 acc[2][2])
{
#pragma unroll
    for (int kk = 0; kk < 4; ++kk) {
        bf8_t av[2], bv[2];
#pragma unroll
        for (int i = 0; i < 2; ++i) {
            const int row = rowA0 + i * 32 + l31;
            const int ch = (kk * 2 + hi) ^ (row & 7);
            av[i] = *(const bf8_t*)(As + row * 64 + ch * 8);
        }
#pragma unroll
        for (int j = 0; j < 2; ++j) {
            const int row = colB0 + j * 32 + l31;
            const int ch = (kk * 2 + hi) ^ (row & 7);
            bv[j] = *(const bf8_t*)(Bs + row * 64 + ch * 8);
        }
#pragma unroll
        for (int i = 0; i < 2; ++i)
#pragma unroll
            for (int j = 0; j < 2; ++j)
                acc[i][j] = __builtin_amdgcn_mfma_f32_32x32x16_bf16(av[i], bv[j], acc[i][j], 0, 0, 0);
    }
}

// ------------------------------------------------------------ MFMA GEMM bf16
// C[M,N] = A[M,K] @ Bt[N,K]^T (+bias)(+relu). 128x128 tile, BK=64, 256 thr.
template<bool BIAS, bool RELU, bool OUTBF>
__global__ __launch_bounds__(256)
void gemm_bf(const ushort* __restrict__ A, int lda,
             const ushort* __restrict__ Bt, int ldb,
             const float* __restrict__ bias,
             void* __restrict__ Cp, int ldc,
             int M, int N, int K)
{
    __shared__ __align__(16) ushort sh[17408];   // staging 32KB / epi [128][136]
    ushort* As = sh;
    ushort* Bs = sh + 8192;
    const int t = threadIdx.x;
    const int w = t >> 6, lane = t & 63;
    const int wr = w >> 1, wc = w & 1;
    const int l31 = lane & 31, hi = lane >> 5;
    const int m0 = blockIdx.y * 128, n0 = blockIdx.x * 128;

    const int srow = w * 8 + (lane >> 3);
    const int gchunk = (lane & 7) ^ (srow & 7);
    const ushort* Ag = A + (size_t)(m0 + srow) * lda + gchunk * 8;
    const ushort* Bg = Bt + (size_t)(n0 + srow) * ldb + gchunk * 8;
    ushort* Asw = As + w * 512;
    ushort* Bsw = Bs + w * 512;

    fx16 acc[2][2];
#pragma unroll
    for (int i = 0; i < 2; ++i)
#pragma unroll
        for (int j = 0; j < 2; ++j)
#pragma unroll
            for (int r = 0; r < 16; ++r) acc[i][j][r] = 0.f;

    for (int k0 = 0; k0 < K; k0 += 64) {
#pragma unroll
        for (int c = 0; c < 4; ++c) {
            gload16(Ag + (size_t)c * 32 * lda, Asw + c * 2048);
            gload16(Bg + (size_t)c * 32 * ldb, Bsw + c * 2048);
        }
        Ag += 64; Bg += 64;
        __syncthreads();
        mma32_step(As, Bs, wr * 64, wc * 64, l31, hi, acc);
        __syncthreads();
    }
    const int crow0 = wr * 64, ccol0 = wc * 64;
    if (OUTBF) {
        ushort* Cs = sh;   // [128][136]
#pragma unroll
        for (int i = 0; i < 2; ++i)
#pragma unroll
            for (int j = 0; j < 2; ++j) {
                const int colb = ccol0 + j * 32 + l31;
                float bb = BIAS ? bias[n0 + colb] : 0.f;
                fx16 v = acc[i][j];
#pragma unroll
                for (int r = 0; r < 16; ++r) {
                    float o = v[r] + bb;
                    if (RELU) o = fmaxf(o, 0.f);
                    const int rw = crow0 + i * 32 + (r & 3) + 8 * (r >> 2) + 4 * hi;
                    Cs[rw * 136 + colb] = f2bf(o);
                }
            }
        __syncthreads();
        const int orow = t >> 1, oc0 = (t & 1) * 64;
        ushort* dst = (ushort*)Cp + (size_t)(m0 + orow) * ldc + n0 + oc0;
#pragma unroll
        for (int u = 0; u < 8; ++u)
            *(bf8_t*)(dst + u * 8) = *(const bf8_t*)(Cs + orow * 136 + oc0 + u * 8);
    } else {
        float* C = (float*)Cp;
#pragma unroll
        for (int i = 0; i < 2; ++i)
#pragma unroll
            for (int j = 0; j < 2; ++j) {
                const int colb = n0 + ccol0 + j * 32 + l31;
                float bb = BIAS ? bias[colb] : 0.f;
                fx16 v = acc[i][j];
#pragma unroll
                for (int r = 0; r < 16; ++r) {
                    float o = v[r] + bb;
                    if (RELU) o = fmaxf(o, 0.f);
                    const int rw = crow0 + i * 32 + (r & 3) + 8 * (r >> 2) + 4 * hi;
                    C[(size_t)(m0 + rw) * ldc + colb] = o;
                }
            }
    }
}

// -------------------------------------- batched r = pos_emb @ Wr[l], 4 layers
// grid (4,4,4): x = n-tile, y = m-tile, z = layer. A [512][512], WrT
// [4][512][512], out R4 [4][512][512]. Removes 4 tiny latency-bound launches.
__global__ __launch_bounds__(256)
void gemm_r4(const ushort* __restrict__ A, const ushort* __restrict__ WrT,
             ushort* __restrict__ R4)
{
    __shared__ __align__(16) ushort sh[17408];
    ushort* As = sh;
    ushort* Bs = sh + 8192;
    const int t = threadIdx.x;
    const int w = t >> 6, lane = t & 63;
    const int wr = w >> 1, wc = w & 1;
    const int l31 = lane & 31, hi = lane >> 5;
    const int m0 = blockIdx.y * 128, n0 = blockIdx.x * 128;
    const ushort* Bt = WrT + (size_t)blockIdx.z * 262144;
    ushort* Cp = R4 + (size_t)blockIdx.z * 262144;

    const int srow = w * 8 + (lane >> 3);
    const int gchunk = (lane & 7) ^ (srow & 7);
    const ushort* Ag = A + (size_t)(m0 + srow) * 512 + gchunk * 8;
    const ushort* Bg = Bt + (size_t)(n0 + srow) * 512 + gchunk * 8;
    ushort* Asw = As + w * 512;
    ushort* Bsw = Bs + w * 512;

    fx16 acc[2][2];
#pragma unroll
    for (int i = 0; i < 2; ++i)
#pragma unroll
        for (int j = 0; j < 2; ++j)
#pragma unroll
            for (int r = 0; r < 16; ++r) acc[i][j][r] = 0.f;

    for (int k0 = 0; k0 < 512; k0 += 64) {
#pragma unroll
        for (int c = 0; c < 4; ++c) {
            gload16(Ag + (size_t)c * 32 * 512, Asw + c * 2048);
            gload16(Bg + (size_t)c * 32 * 512, Bsw + c * 2048);
        }
        Ag += 64; Bg += 64;
        __syncthreads();
        mma32_step(As, Bs, wr * 64, wc * 64, l31, hi, acc);
        __syncthreads();
    }
    const int crow0 = wr * 64, ccol0 = wc * 64;
    ushort* Cs = sh;   // [128][136]
#pragma unroll
    for (int i = 0; i < 2; ++i)
#pragma unroll
        for (int j = 0; j < 2; ++j) {
            const int colb = ccol0 + j * 32 + l31;
            fx16 v = acc[i][j];
#pragma unroll
            for (int r = 0; r < 16; ++r) {
                const int rw = crow0 + i * 32 + (r & 3) + 8 * (r >> 2) + 4 * hi;
                Cs[rw * 136 + colb] = f2bf(v[r]);
            }
        }
    __syncthreads();
    const int orow = t >> 1, oc0 = (t & 1) * 64;
    ushort* dst = Cp + (size_t)(m0 + orow) * 512 + n0 + oc0;
#pragma unroll
    for (int u = 0; u < 8; ++u)
        *(bf8_t*)(dst + u * 8) = *(const bf8_t*)(Cs + orow * 136 + oc0 + u * 8);
}

// ---------------------------------------------- fused q|kv GEMM (col-routed)
// A = curb [8192][512]; Bt = wqkvT_l [1536][512]. Cols 0..511 -> qb [8192][512];
// cols 512..1535 -> kvb rows 8192.. [.][1024]. grid (12,64), 3 blocks/CU.
__global__ __launch_bounds__(256)
void gemm_qkv(const ushort* __restrict__ A, const ushort* __restrict__ Bt,
              ushort* __restrict__ qout, ushort* __restrict__ kvout)
{
    __shared__ __align__(16) ushort sh[17408];
    ushort* As = sh;
    ushort* Bs = sh + 8192;
    const int t = threadIdx.x;
    const int w = t >> 6, lane = t & 63;
    const int wr = w >> 1, wc = w & 1;
    const int l31 = lane & 31, hi = lane >> 5;
    const int m0 = blockIdx.y * 128, n0 = blockIdx.x * 128;

    const int srow = w * 8 + (lane >> 3);
    const int gchunk = (lane & 7) ^ (srow & 7);
    const ushort* Ag = A + (size_t)(m0 + srow) * 512 + gchunk * 8;
    const ushort* Bg = Bt + (size_t)(n0 + srow) * 512 + gchunk * 8;
    ushort* Asw = As + w * 512;
    ushort* Bsw = Bs + w * 512;

    fx16 acc[2][2];
#pragma unroll
    for (int i = 0; i < 2; ++i)
#pragma unroll
        for (int j = 0; j < 2; ++j)
#pragma unroll
            for (int r = 0; r < 16; ++r) acc[i][j][r] = 0.f;

    for (int k0 = 0; k0 < 512; k0 += 64) {
#pragma unroll
        for (int c = 0; c < 4; ++c) {
            gload16(Ag + (size_t)c * 32 * 512, Asw + c * 2048);
            gload16(Bg + (size_t)c * 32 * 512, Bsw + c * 2048);
        }
        Ag += 64; Bg += 64;
        __syncthreads();
        mma32_step(As, Bs, wr * 64, wc * 64, l31, hi, acc);
        __syncthreads();
    }
    const int crow0 = wr * 64, ccol0 = wc * 64;
    ushort* Cs = sh;   // [128][136]
#pragma unroll
    for (int i = 0; i < 2; ++i)
#pragma unroll
        for (int j = 0; j < 2; ++j) {
            const int colb = ccol0 + j * 32 + l31;
            fx16 v = acc[i][j];
#pragma unroll
            for (int r = 0; r < 16; ++r) {
                const int rw = crow0 + i * 32 + (r & 3) + 8 * (r >> 2) + 4 * hi;
                Cs[rw * 136 + colb] = f2bf(v[r]);
            }
        }
    __syncthreads();
    ushort* base; size_t ldc2;
    if (n0 < 512) { base = qout + n0; ldc2 = 512; }
    else          { base = kvout + (size_t)8192 * 1024 + (n0 - 512); ldc2 = 1024; }
    const int orow = t >> 1, oc0 = (t & 1) * 64;
    ushort* dst = base + (size_t)(m0 + orow) * ldc2 + oc0;
#pragma unroll
    for (int u = 0; u < 8; ++u)
        *(bf8_t*)(dst + u * 8) = *(const bf8_t*)(Cs + orow * 136 + oc0 + u * 8);
}

// ------------------------------------------------ split-K GEMM (f32 partials)
// z = blockIdx.z selects K-half; z=0 -> C0 (+bias), z=1 -> C1. KH = K/2.
template<bool BIAS>
__global__ __launch_bounds__(256)
void gemm_sk(const ushort* __restrict__ A, int lda,
             const ushort* __restrict__ Bt, int ldb,
             const float* __restrict__ bias,
             float* __restrict__ C0, float* __restrict__ C1, int ldc, int KH)
{
    __shared__ __align__(16) ushort sh[16384];
    ushort* As = sh;
    ushort* Bs = sh + 8192;
    const int t = threadIdx.x;
    const int w = t >> 6, lane = t & 63;
    const int wr = w >> 1, wc = w & 1;
    const int l31 = lane & 31, hi = lane >> 5;
    const int m0 = blockIdx.y * 128, n0 = blockIdx.x * 128;
    const int z = blockIdx.z;
    A += (size_t)z * KH; Bt += (size_t)z * KH;
    float* C = z ? C1 : C0;

    const int srow = w * 8 + (lane >> 3);
    const int gchunk = (lane & 7) ^ (srow & 7);
    const ushort* Ag = A + (size_t)(m0 + srow) * lda + gchunk * 8;
    const ushort* Bg = Bt + (size_t)(n0 + srow) * ldb + gchunk * 8;
    ushort* Asw = As + w * 512;
    ushort* Bsw = Bs + w * 512;

    fx16 acc[2][2];
#pragma unroll
    for (int i = 0; i < 2; ++i)
#pragma unroll
        for (int j = 0; j < 2; ++j)
#pragma unroll
            for (int r = 0; r < 16; ++r) acc[i][j][r] = 0.f;

    for (int k0 = 0; k0 < KH; k0 += 64) {
#pragma unroll
        for (int c = 0; c < 4; ++c) {
            gload16(Ag + (size_t)c * 32 * lda, Asw + c * 2048);
            gload16(Bg + (size_t)c * 32 * ldb, Bsw + c * 2048);
        }
        Ag += 64; Bg += 64;
        __syncthreads();
        mma32_step(As, Bs, wr * 64, wc * 64, l31, hi, acc);
        __syncthreads();
    }
    const int crow0 = wr * 64, ccol0 = wc * 64;
#pragma unroll
    for (int i = 0; i < 2; ++i)
#pragma unroll
        for (int j = 0; j < 2; ++j) {
            const int colb = n0 + ccol0 + j * 32 + l31;
            float bb = (BIAS && z == 0) ? bias[colb] : 0.f;
            fx16 v = acc[i][j];
#pragma unroll
            for (int r = 0; r < 16; ++r) {
                const int rw = crow0 + i * 32 + (r & 3) + 8 * (r >> 2) + 4 * hi;
                C[(size_t)(m0 + rw) * ldc + colb] = v[r] + bb;
            }
        }
}

// ---------------------------------------------------------------- LayerNorm
// RMODE: 0 X; 1 X+Rf32; 2 X+Rbf16; 3 X+X2+Rbf16; 4 X+X2+Rf32.
// TROUT: f32 out transposed to [B,L].
template<int RMODE, bool TROUT>
__global__ __launch_bounds__(256)
void ln_k(const float* __restrict__ X, const float* __restrict__ X2,
          const void* __restrict__ Rp,
          const float* __restrict__ g, const float* __restrict__ bt,
          float* __restrict__ Yf, ushort* __restrict__ Yb,
          float eps, int do_relu)
{
    const int row  = blockIdx.x * 4 + (threadIdx.x >> 6);
    const int lane = threadIdx.x & 63;
    const float* xp = X + (size_t)row * 512 + lane * 8;
    float4 x0 = *(const float4*)xp, x1 = *(const float4*)(xp + 4);
    float v[8] = {x0.x, x0.y, x0.z, x0.w, x1.x, x1.y, x1.z, x1.w};
    if (RMODE == 3 || RMODE == 4) {
        const float* p2 = X2 + (size_t)row * 512 + lane * 8;
        float4 a0 = *(const float4*)p2, a1 = *(const float4*)(p2 + 4);
        v[0] += a0.x; v[1] += a0.y; v[2] += a0.z; v[3] += a0.w;
        v[4] += a1.x; v[5] += a1.y; v[6] += a1.z; v[7] += a1.w;
    }
    if (RMODE == 1 || RMODE == 4) {
        const float* rp = (const float*)Rp + (size_t)row * 512 + lane * 8;
        float4 r0 = *(const float4*)rp, r1 = *(const float4*)(rp + 4);
        v[0] += r0.x; v[1] += r0.y; v[2] += r0.z; v[3] += r0.w;
        v[4] += r1.x; v[5] += r1.y; v[6] += r1.z; v[7] += r1.w;
    } else if (RMODE == 2 || RMODE == 3) {
        const ushort* rp = (const ushort*)Rp + (size_t)row * 512 + lane * 8;
        ushort4 r0 = *(const ushort4*)rp, r1 = *(const ushort4*)(rp + 4);
        v[0] += b2f(r0.x); v[1] += b2f(r0.y); v[2] += b2f(r0.z); v[3] += b2f(r0.w);
        v[4] += b2f(r1.x); v[5] += b2f(r1.y); v[6] += b2f(r1.z); v[7] += b2f(r1.w);
    }
    float s = 0.f;
#pragma unroll
    for (int i = 0; i < 8; ++i) s += v[i];
#pragma unroll
    for (int m = 1; m < 64; m <<= 1) s += __shfl_xor(s, m);
    float mean = s * (1.f / 512.f);
    float q = 0.f;
#pragma unroll
    for (int i = 0; i < 8; ++i) { float d = v[i] - mean; q = fmaf(d, d, q); }
#pragma unroll
    for (int m = 1; m < 64; m <<= 1) q += __shfl_xor(q, m);
    float rstd = rsqrtf(q * (1.f / 512.f) + eps);
    float4 g0 = *(const float4*)(g + lane * 8), g1 = *(const float4*)(g + lane * 8 + 4);
    float4 c0 = *(const float4*)(bt + lane * 8), c1 = *(const float4*)(bt + lane * 8 + 4);
    float gv[8] = {g0.x, g0.y, g0.z, g0.w, g1.x, g1.y, g1.z, g1.w};
    float bv[8] = {c0.x, c0.y, c0.z, c0.w, c1.x, c1.y, c1.z, c1.w};
    float o[8];
#pragma unroll
    for (int i = 0; i < 8; ++i) {
        o[i] = (v[i] - mean) * rstd * gv[i] + bv[i];
        if (do_relu) o[i] = fmaxf(o[i], 0.f);
    }
    if (Yf) {
        float* yp;
        if (TROUT) {
            const int bq = row & 31, lq = row >> 5;
            yp = Yf + ((size_t)bq * 256 + lq) * 512 + lane * 8;
        } else {
            yp = Yf + (size_t)row * 512 + lane * 8;
        }
        *(float4*)yp       = make_float4(o[0], o[1], o[2], o[3]);
        *(float4*)(yp + 4) = make_float4(o[4], o[5], o[6], o[7]);
    }
    if (Yb) {
        ushort* yp = Yb + (size_t)row * 512 + lane * 8;
        ushort4 w0, w1;
        w0.x = f2bf(o[0]); w0.y = f2bf(o[1]); w0.z = f2bf(o[2]); w0.w = f2bf(o[3]);
        w1.x = f2bf(o[4]); w1.y = f2bf(o[5]); w1.z = f2bf(o[6]); w1.w = f2bf(o[7]);
        *(ushort4*)yp       = w0;
        *(ushort4*)(yp + 4) = w1;
    }
}

// ------------------------------------------ fused stem double LN (ln2 -> lnf)
__global__ __launch_bounds__(256)
void ln_stem2(const float* __restrict__ X,
              const float* __restrict__ g1, const float* __restrict__ b1,
              const float* __restrict__ g2, const float* __restrict__ b2,
              float* __restrict__ Yf, ushort* __restrict__ Yb)
{
    const int row  = blockIdx.x * 4 + (threadIdx.x >> 6);
    const int lane = threadIdx.x & 63;
    const float* xp = X + (size_t)row * 512 + lane * 8;
    float4 x0 = *(const float4*)xp, x1 = *(const float4*)(xp + 4);
    float v[8] = {x0.x, x0.y, x0.z, x0.w, x1.x, x1.y, x1.z, x1.w};
    float s = 0.f;
#pragma unroll
    for (int i = 0; i < 8; ++i) s += v[i];
#pragma unroll
    for (int m = 1; m < 64; m <<= 1) s += __shfl_xor(s, m);
    float mean = s * (1.f / 512.f);
    float q = 0.f;
#pragma unroll
    for (int i = 0; i < 8; ++i) { float d = v[i] - mean; q = fmaf(d, d, q); }
#pragma unroll
    for (int m = 1; m < 64; m <<= 1) q += __shfl_xor(q, m);
    float rstd = rsqrtf(q * (1.f / 512.f) + 1e-5f);
#pragma unroll
    for (int i = 0; i < 8; ++i)
        v[i] = (v[i] - mean) * rstd * g1[lane * 8 + i] + b1[lane * 8 + i];
    s = 0.f;
#pragma unroll
    for (int i = 0; i < 8; ++i) s += v[i];
#pragma unroll
    for (int m = 1; m < 64; m <<= 1) s += __shfl_xor(s, m);
    mean = s * (1.f / 512.f);
    q = 0.f;
#pragma unroll
    for (int i = 0; i < 8; ++i) { float d = v[i] - mean; q = fmaf(d, d, q); }
#pragma unroll
    for (int m = 1; m < 64; m <<= 1) q += __shfl_xor(q, m);
    rstd = rsqrtf(q * (1.f / 512.f) + 1e-6f);
    float o[8];
#pragma unroll
    for (int i = 0; i < 8; ++i)
        o[i] = (v[i] - mean) * rstd * g2[lane * 8 + i] + b2[lane * 8 + i];
    float* yp = Yf + (size_t)row * 512 + lane * 8;
    *(float4*)yp       = make_float4(o[0], o[1], o[2], o[3]);
    *(float4*)(yp + 4) = make_float4(o[4], o[5], o[6], o[7]);
    ushort* yb = Yb + (size_t)row * 512 + lane * 8;
    ushort4 w0, w1;
    w0.x = f2bf(o[0]); w0.y = f2bf(o[1]); w0.z = f2bf(o[2]); w0.w = f2bf(o[3]);
    w1.x = f2bf(o[4]); w1.y = f2bf(o[5]); w1.z = f2bf(o[6]); w1.w = f2bf(o[7]);
    *(ushort4*)yb       = w0;
    *(ushort4*)(yb + 4) = w1;
}

// ---------------------------------------------- weight transpose+cast f32->bf16
__global__ __launch_bounds__(256)
void wtrans(const float* __restrict__ in, ushort* __restrict__ out, int K, int N)
{
    __shared__ float tl[32][33];
    const size_t bo = (size_t)blockIdx.z * K * N;
    in += bo; out += bo;
    const int k0 = blockIdx.y * 32, n0 = blockIdx.x * 32;
    const int tx = threadIdx.x & 31, ty = threadIdx.x >> 5;
    for (int i = ty; i < 32; i += 8) tl[i][tx] = in[(size_t)(k0 + i) * N + n0 + tx];
    __syncthreads();
    for (int i = ty; i < 32; i += 8) out[(size_t)(n0 + i) * K + k0 + tx] = f2bf(tl[tx][i]);
}

__global__ void convk(const float* __restrict__ in, ushort* __restrict__ out)
{
    int i = (blockIdx.x * 256 + threadIdx.x) * 4;
    float4 v = *(const float4*)(in + i);
    ushort4 o;
    o.x = f2bf(v.x); o.y = f2bf(v.y); o.z = f2bf(v.z); o.w = f2bf(v.w);
    *(ushort4*)(out + i) = o;
}

// ----------------------------------------------------- stem concat [x | act]
__global__ void build_xcat(const float* __restrict__ x, const int* __restrict__ action,
                           const float* __restrict__ act_emb, ushort* __restrict__ xcat)
{
    int idx = blockIdx.x * 256 + threadIdx.x;           // 8192*576
    int n = idx / 576, e = idx - n * 576;
    int l = n >> 5, b = n & 31;
    float v;
    if (e < 512) v = x[((size_t)b * 256 + l) * 512 + e];
    else         v = act_emb[action[b * 32 + (l >> 3)] * 64 + (e - 512)];
    xcat[idx] = f2bf(v);
}

// ------------------------------------------------- sinusoidal pos embedding
__global__ void build_posemb(ushort* __restrict__ pe)
{
    int idx = blockIdx.x * 256 + threadIdx.x;           // 512*512
    int j = idx >> 9, c = idx & 511;
    float pf = (float)(511 - j);
    int i2 = (c < 256) ? c : c - 256;
    float inv = expf(-(float)i2 * 0.03597789207803197f);
    float ang = pf * inv;
    pe[idx] = f2bf((c < 256) ? sinf(ang) : cosf(ang));
}

// --------------------------------------------------- MFMA flash attention
// r7 kernel (proven 66 us) + T5 setprio around MFMA clusters.
// block = (b*8+h)*2 + ihalf; 8 waves; Rs rolling 3-slab band; T14 prefetch.
__global__ __launch_bounds__(512)
void attn_mfma(const ushort* __restrict__ q,    // [256*32][512]
               const ushort* __restrict__ kv,   // [512*32][1024]  k | v halves
               const ushort* __restrict__ rb,   // [512][512]
               const float* __restrict__ ub, const float* __restrict__ vb,
               ushort* __restrict__ ao)         // [256*32][512]
{
    __shared__ __align__(16) ushort Ks[64][72];     // K tile  [j][d]
    __shared__ __align__(16) ushort Vs[64][72];     // V^T tile [d][j]
    __shared__ __align__(16) ushort Rs[192][72];    // rolling r band (3 slabs)
    __shared__ __align__(16) ushort Ps[8][16][72];  // per-wave P / O bounce
    const int t = threadIdx.x;
    const int wv = t >> 6, lane = t & 63;
    const int lc = lane & 15, lr = lane >> 4;
    const int bh = (int)blockIdx.x >> 1, ihalf = blockIdx.x & 1;
    const int b = bh >> 3, h = bh & 7;
    const int i0 = ihalf << 7;
    const int iw = i0 + wv * 16;

    // q A-fragments with u/v bias folded
    bf8_t au[2], aw[2];
#pragma unroll
    for (int kk = 0; kk < 2; ++kk) {
        const ushort* qp = q + ((size_t)(iw + lc) * 32 + b) * 512 + h * 64 + kk * 32 + lr * 8;
        bf8_t q8 = *(const bf8_t*)qp;
        const float* up = ub + h * 64 + kk * 32 + lr * 8;
        const float* vp = vb + h * 64 + kk * 32 + lr * 8;
#pragma unroll
        for (int e = 0; e < 8; ++e) {
            float qf = b2f((ushort)q8[e]);
            au[kk][e] = (short)f2bf(qf + up[e]);
            aw[kk][e] = (short)f2bf(qf + vp[e]);
        }
    }

    // staging indices
    const int jl = t >> 3, d0 = (t & 7) * 8;
    const int vrow = ((t >> 3) & 7) * 8 + wv;

    f4_t o[4];
#pragma unroll
    for (int d = 0; d < 4; ++d) o[d] = (f4_t){0.f, 0.f, 0.f, 0.f};
    float mrun[4] = {-3.0e38f, -3.0e38f, -3.0e38f, -3.0e38f};
    float lrun[4] = {0.f, 0.f, 0.f, 0.f};

    // ---- prologue: stage tile 0 (K, V^T, all 3 R slabs) ----
    {
        *(bf8_t*)&Ks[jl][d0] = *(const bf8_t*)(kv + ((size_t)jl * 32 + b) * 1024 + h * 64 + d0);
        bf8_t vv = *(const bf8_t*)(kv + ((size_t)vrow * 32 + b) * 1024 + 512 + h * 64 + d0);
#pragma unroll
        for (int e = 0; e < 8; ++e) Vs[d0 + e][vrow] = (ushort)vv[e];
        const int rbase0 = 128 - i0;
#pragma unroll
        for (int p = 0; p < 3; ++p) {
            const int jr = min(rbase0 + p * 64 + jl, 511);
            *(bf8_t*)&Rs[p * 64 + jl][d0] = *(const bf8_t*)(rb + (size_t)jr * 512 + h * 64 + d0);
        }
    }
    __syncthreads();

    const int njt = ihalf ? 8 : 6;
    for (int jt = 0; jt < njt; ++jt) {
        const int j0 = jt << 6;
        // ---- prefetch next tile into registers (overlaps compute below) ----
        bf8_t pk, pv, pr;
        const bool pfq = (jt + 1 < njt);
        if (pfq) {
            const int j0n = j0 + 64;
            pk = *(const bf8_t*)(kv + ((size_t)(j0n + jl) * 32 + b) * 1024 + h * 64 + d0);
            pv = *(const bf8_t*)(kv + ((size_t)(j0n + vrow) * 32 + b) * 1024 + 512 + h * 64 + d0);
            const int jr = min(j0n - i0 + 256 + jl, 511);
            pr = *(const bf8_t*)(rb + (size_t)jr * 512 + h * 64 + d0);
        }
        // ---- compute on tile jt ----
        if (j0 <= iw + 271) {
            f4_t acf[4], bdf[5];
#pragma unroll
            for (int jj = 0; jj < 4; ++jj) acf[jj] = (f4_t){0.f, 0.f, 0.f, 0.f};
#pragma unroll
            for (int fj = 0; fj < 5; ++fj) bdf[fj] = (f4_t){0.f, 0.f, 0.f, 0.f};
            __builtin_amdgcn_s_setprio(1);
#pragma unroll
            for (int jj = 0; jj < 4; ++jj)
#pragma unroll
                for (int kk = 0; kk < 2; ++kk) {
                    bf8_t kf = *(const bf8_t*)&Ks[jj * 16 + lc][kk * 32 + lr * 8];
                    acf[jj] = __builtin_amdgcn_mfma_f32_16x16x32_bf16(au[kk], kf, acf[jj], 0, 0, 0);
                }
            const int rboff = 112 - wv * 16;
#pragma unroll
            for (int fj = 0; fj < 5; ++fj) {
                const int lbase = rboff + fj * 16;
                const int prow = ((jt + (lbase >> 6)) % 3) * 64 + (lbase & 63) + lc;
#pragma unroll
                for (int kk = 0; kk < 2; ++kk) {
                    bf8_t rf = *(const bf8_t*)&Rs[prow][kk * 32 + lr * 8];
                    bdf[fj] = __builtin_amdgcn_mfma_f32_16x16x32_bf16(aw[kk], rf, bdf[fj], 0, 0, 0);
                }
            }
            __builtin_amdgcn_s_setprio(0);
            // ---- rel-shift shuffle + mask + online softmax ----
            float pm[4][4];
            float mt[4] = {-3.0e38f, -3.0e38f, -3.0e38f, -3.0e38f};
            const int jbase = j0 + lc - iw - 256;
#pragma unroll
            for (int rg = 0; rg < 4; ++rg) {
                const int il = lr * 4 + rg;
                const int srcl = (lane & 48) | ((lc + 15 - il) & 15);
                float shf[5];
#pragma unroll
                for (int fj = 0; fj < 5; ++fj) shf[fj] = __shfl(bdf[fj][rg], srcl, 64);
#pragma unroll
                for (int jj = 0; jj < 4; ++jj) {
                    float bd = (lc > il) ? shf[jj + 1] : shf[jj];
                    float s = (acf[jj][rg] + bd) * 0.125f;
                    if (jbase + jj * 16 > il) s = -1e30f;
                    pm[jj][rg] = s;
                    mt[rg] = fmaxf(mt[rg], s);
                }
            }
            float corr[4];
#pragma unroll
            for (int rg = 0; rg < 4; ++rg) {
#pragma unroll
                for (int mm = 1; mm < 16; mm <<= 1)
                    mt[rg] = fmaxf(mt[rg], __shfl_xor(mt[rg], mm, 64));
                float mnew = fmaxf(mrun[rg], mt[rg]);
                corr[rg] = __expf(mrun[rg] - mnew);
                mrun[rg] = mnew;
            }
            float ps4[4] = {0.f, 0.f, 0.f, 0.f};
#pragma unroll
            for (int jj = 0; jj < 4; ++jj)
#pragma unroll
                for (int rg = 0; rg < 4; ++rg) {
                    float p = __expf(pm[jj][rg] - mrun[rg]);
                    ps4[rg] += p;
                    Ps[wv][lr * 4 + rg][jj * 16 + lc] = f2bf(p);
                }
#pragma unroll
            for (int rg = 0; rg < 4; ++rg) {
#pragma unroll
                for (int mm = 1; mm < 16; mm <<= 1)
                    ps4[rg] += __shfl_xor(ps4[rg], mm, 64);
                lrun[rg] = lrun[rg] * corr[rg] + ps4[rg];
            }
            float c0 = __shfl(corr[0], (lc >> 2) << 4, 64);
            float c1 = __shfl(corr[1], (lc >> 2) << 4, 64);
            float c2 = __shfl(corr[2], (lc >> 2) << 4, 64);
            float c3 = __shfl(corr[3], (lc >> 2) << 4, 64);
            float myc = (lc & 2) ? ((lc & 1) ? c3 : c2) : ((lc & 1) ? c1 : c0);
#pragma unroll
            for (int db = 0; db < 4; ++db)
#pragma unroll
                for (int rg = 0; rg < 4; ++rg) o[db][rg] *= myc;
            __builtin_amdgcn_s_setprio(1);
#pragma unroll
            for (int kb = 0; kb < 2; ++kb) {
                bf8_t pf = *(const bf8_t*)&Ps[wv][lc][kb * 32 + lr * 8];
#pragma unroll
                for (int db = 0; db < 4; ++db) {
                    bf8_t vf = *(const bf8_t*)&Vs[db * 16 + lc][kb * 32 + lr * 8];
                    o[db] = __builtin_amdgcn_mfma_f32_16x16x32_bf16(vf, pf, o[db], 0, 0, 0);
                }
            }
            __builtin_amdgcn_s_setprio(0);
        }
        __syncthreads();                 // all waves done reading LDS tile jt
        if (pfq) {                       // write prefetched tile jt+1
            *(bf8_t*)&Ks[jl][d0] = pk;
#pragma unroll
            for (int e = 0; e < 8; ++e) Vs[d0 + e][vrow] = (ushort)pv[e];
            const int phys = (jt % 3) * 64 + jl;     // slab for logical band top
            *(bf8_t*)&Rs[phys][d0] = pr;
        }
        __syncthreads();                 // writes visible before next compute
    }
    // ---- epilogue: scale by 1/l, bounce O^T -> row-major via Ps, store ----
    float i4[4];
#pragma unroll
    for (int rg = 0; rg < 4; ++rg) i4[rg] = 1.f / lrun[rg];
    float s0 = __shfl(i4[0], (lc >> 2) << 4, 64);
    float s1 = __shfl(i4[1], (lc >> 2) << 4, 64);
    float s2 = __shfl(i4[2], (lc >> 2) << 4, 64);
    float s3 = __shfl(i4[3], (lc >> 2) << 4, 64);
    float myi = (lc & 2) ? ((lc & 1) ? s3 : s2) : ((lc & 1) ? s1 : s0);
#pragma unroll
    for (int db = 0; db < 4; ++db)
#pragma unroll
        for (int rg = 0; rg < 4; ++rg)
            Ps[wv][lc][db * 16 + lr * 4 + rg] = f2bf(o[db][rg] * myi);
    const int il2 = lane >> 2, dsg = (lane & 3) << 4;
    bf8_t e0 = *(const bf8_t*)&Ps[wv][il2][dsg];
    bf8_t e1 = *(const bf8_t*)&Ps[wv][il2][dsg + 8];
    ushort* dst = ao + ((size_t)(iw + il2) * 32 + b) * 512 + h * 64 + dsg;
    *(bf8_t*)dst = e0;
    *(bf8_t*)(dst + 8) = e1;
}

// ---------------------------------------------------------------------------
extern "C" void kernel_launch(void* const* d_in, const int* in_sizes, int n_in,
                              void* d_out, int out_size, void* d_ws, size_t ws_size,
                              hipStream_t stream)
{
    const float* x       = (const float*)d_in[0];
    const int*   action  = (const int*)d_in[1];
    const float* mems    = (const float*)d_in[4];
    const float* act_emb = (const float*)d_in[5];
    const float* stem_w1 = (const float*)d_in[6];
    const float* sln1g   = (const float*)d_in[7];
    const float* sln1b   = (const float*)d_in[8];
    const float* stem_w2 = (const float*)d_in[9];
    const float* sln2g   = (const float*)d_in[10];
    const float* sln2b   = (const float*)d_in[11];
    const float* lnfg    = (const float*)d_in[12];
    const float* lnfb    = (const float*)d_in[13];
    const float* ub      = (const float*)d_in[14];
    const float* vb      = (const float*)d_in[15];
    const float* Wqkv    = (const float*)d_in[16];
    const float* Wr      = (const float*)d_in[17];
    const float* Wo      = (const float*)d_in[18];
    const float* ln1g    = (const float*)d_in[19];
    const float* ln1b    = (const float*)d_in[20];
    const float* W1      = (const float*)d_in[21];
    const float* b1      = (const float*)d_in[22];
    const float* W2      = (const float*)d_in[23];
    const float* b2      = (const float*)d_in[24];
    const float* ln2g    = (const float*)d_in[25];
    const float* ln2b    = (const float*)d_in[26];
    float* out = (float*)d_out;

    // ---- workspace layout (bytes), total ~123.8 MB (round-1 proved >=130) ----
    char* W = (char*)d_ws;
    float*  cur32 = (float*) (W + 0);           // 16 MB residual f32 / FF2 partial
    float*  g32   = (float*) (W + 16777216);    // 16 MB gemm f32 scratch (hosts memsb)
    ushort* curb  = (ushort*)(W + 33554432);    //  8 MB cur bf16
    ushort* h1b   = (ushort*)(W + 41943040);    //  8 MB h1/ao bf16
    ushort* qb    = (ushort*)(W + 50331648);    //  8 MB q bf16 [8192][512]
    ushort* kvb   = (ushort*)(W + 58720256);    // 32 MB kv bf16 [16384][1024]
    ushort* rbufx = (ushort*)(W + 92274688);    // (old rbuf slot, unused)
    ushort* peb   = (ushort*)(W + 92798976);    // 512 KB
    ushort* wts   = (ushort*)(W + 93323264);    // 27 MB transposed bf16 weights
    ushort* rbuf4 = (ushort*)(W + 121700352);   //  2 MB [4][512][512] r per layer
    ushort* xcatb = kvb;                        // stem alias (dead before kv use)
    ushort* ff1b  = kvb;                        // FF1 alias (kv dead post-attn)
    float*  wopart = (float*)kvb;               // Wo split-K partial (post-attn)
    ushort* memsb = (ushort*)g32;               // alias (g32 dead at layer start)
    ushort* w1t    = wts;                       // [512][576]
    ushort* w2t    = wts + 294912;              // [512][512]
    ushort* wqkvT  = wts + 557056;              // [4][1536][512]
    ushort* wrT    = wts + 3702784;             // [4][512][512]
    ushort* woT    = wts + 4751360;             // [4][512][512]
    ushort* w1T    = wts + 5799936;             // [4][2048][512]
    ushort* w2T    = wts + 9994240;             // [4][512][2048]
    (void)rbufx;

    dim3 blk(256);
    wtrans<<<dim3(16, 18, 1), blk, 0, stream>>>(stem_w1, w1t, 576, 512);
    wtrans<<<dim3(16, 16, 1), blk, 0, stream>>>(stem_w2, w2t, 512, 512);
    wtrans<<<dim3(48, 16, 4), blk, 0, stream>>>(Wqkv, wqkvT, 512, 1536);
    wtrans<<<dim3(16, 16, 4), blk, 0, stream>>>(Wr, wrT, 512, 512);
    wtrans<<<dim3(16, 16, 4), blk, 0, stream>>>(Wo, woT, 512, 512);
    wtrans<<<dim3(64, 16, 4), blk, 0, stream>>>(W1, w1T, 512, 2048);
    wtrans<<<dim3(16, 64, 4), blk, 0, stream>>>(W2, w2T, 2048, 512);
    build_posemb<<<1024, blk, 0, stream>>>(peb);
    // all 4 layers' r = pos_emb @ Wr[l] in one dispatch (64 blocks)
    gemm_r4<<<dim3(4, 4, 4), blk, 0, stream>>>(peb, wrT, rbuf4);

    build_xcat<<<18432, blk, 0, stream>>>(x, action, act_emb, xcatb);
    gemm_bf<false, false, false><<<dim3(4, 64), blk, 0, stream>>>(xcatb, 576, w1t, 576, nullptr, g32, 512, 8192, 512, 576);
    ln_k<0, false><<<2048, blk, 0, stream>>>(g32, nullptr, nullptr, sln1g, sln1b, nullptr, curb, 1e-5f, 1);
    gemm_bf<false, false, false><<<dim3(4, 64), blk, 0, stream>>>(curb, 512, w2t, 512, nullptr, g32, 512, 8192, 512, 512);
    ln_stem2<<<2048, blk, 0, stream>>>(g32, sln2g, sln2b, lnfg, lnfb, cur32, curb);

    for (int l = 0; l < 4; ++l) {
        const ushort* wqkvT_l = wqkvT + (size_t)l * 786432;
        convk<<<4096, blk, 0, stream>>>(mems + (size_t)l * 4194304, memsb);
        // fused q | kv(cur) -> qb and kvb rows 8192..
        gemm_qkv<<<dim3(12, 64), blk, 0, stream>>>(curb, wqkvT_l, qb, kvb);
        // kv(mems) -> kvb rows 0..8191
        gemm_bf<false, false, true><<<dim3(8, 64), blk, 0, stream>>>(memsb, 512, wqkvT_l + 262144, 512, nullptr, kvb, 1024, 8192, 1024, 512);
        attn_mfma<<<512, dim3(512), 0, stream>>>(qb, kvb, rbuf4 + (size_t)l * 262144, ub, vb, h1b);
        // Wo split-K: z0 -> g32, z1 -> wopart (kvb region, dead post-attn)
        gemm_sk<false><<<dim3(4, 64, 2), blk, 0, stream>>>(h1b, 512, woT + (size_t)l * 262144, 512, nullptr, g32, wopart, 512, 256);
        ln_k<4, false><<<2048, blk, 0, stream>>>(g32, wopart, cur32, ln1g + l * 512, ln1b + l * 512, nullptr, h1b, 1e-5f, 0);
        gemm_bf<true, true, true><<<dim3(16, 64), blk, 0, stream>>>(h1b, 512, w1T + (size_t)l * 1048576, 512, b1 + l * 2048, ff1b, 2048, 8192, 2048, 512);
        // FF2 split-K: z0 -> g32 (+bias), z1 -> cur32 (residual dead after ln1)
        gemm_sk<true><<<dim3(4, 64, 2), blk, 0, stream>>>(ff1b, 2048, w2T + (size_t)l * 1048576, 2048, b2 + l * 512, g32, cur32, 512, 1024);
        if (l == 3)
            ln_k<3, true><<<2048, blk, 0, stream>>>(g32, cur32, h1b, ln2g + l * 512, ln2b + l * 512, out, nullptr, 1e-5f, 0);
        else
            ln_k<3, false><<<2048, blk, 0, stream>>>(g32, cur32, h1b, ln2g + l * 512, ln2b + l * 512, cur32, curb, 1e-5f, 0);
    }
}

// Round 13
// 869.050 us; speedup vs baseline: 1.1048x; 1.0125x over previous
//
#include <hip/hip_runtime.h>

// TransformerXL forward, MI355X. Round 13: attn Vs XOR-swizzle (kills the
// 8-way V^T write conflict diagnosed from SQ_LDS_BANK_CONFLICT=6.5M) +
// XCD-aware block remap (each XCD owns 4 batches' kv slice -> L2-fit).
// Everything else identical to r12 (880 us).
// L=256, KLEN=512, B=32, E=512, H=8, D=64, FF=2048, NL=4.

typedef __attribute__((ext_vector_type(8))) short bf8_t;    // 8 bf16 in 4 VGPRs
typedef __attribute__((ext_vector_type(4))) float f4_t;
typedef __attribute__((ext_vector_type(16))) float fx16;    // 32x32 accum

__device__ __forceinline__ ushort f2bf(float f) {           // RNE f32->bf16
    uint u = __float_as_uint(f);
    u += 0x7FFFu + ((u >> 16) & 1u);
    return (ushort)(u >> 16);
}
__device__ __forceinline__ float b2f(ushort h) {
    return __uint_as_float(((uint)h) << 16);
}
__device__ __forceinline__ void gload16(const void* g, void* l) {
    __builtin_amdgcn_global_load_lds((const __attribute__((address_space(1))) void*)g,
                                     (__attribute__((address_space(3))) void*)l, 16, 0, 0);
}

// ---------------- shared 32x32x16 MFMA core for one BK=64 step -------------
__device__ __forceinline__ void mma32_step(const ushort* __restrict__ As,
                                           const ushort* __restrict__ Bs,
                                           int rowA0, int colB0,
                                           int l31, int hi, fx16 acc[2][2])
{
#pragma unroll
    for (int kk = 0; kk < 4; ++kk) {
        bf8_t av[2], bv[2];
#pragma unroll
        for (int i = 0; i < 2; ++i) {
            const int row = rowA0 + i * 32 + l31;
            const int ch = (kk * 2 + hi) ^ (row & 7);
            av[i] = *(const bf8_t*)(As + row * 64 + ch * 8);
        }
#pragma unroll
        for (int j = 0; j < 2; ++j) {
            const int row = colB0 + j * 32 + l31;
            const int ch = (kk * 2 + hi) ^ (row & 7);
            bv[j] = *(const bf8_t*)(Bs + row * 64 + ch * 8);
        }
#pragma unroll
        for (int i = 0; i < 2; ++i)
#pragma unroll
            for (int j = 0; j < 2; ++j)
                acc[i][j] = __builtin_amdgcn_mfma_f32_32x32x16_bf16(av[i], bv[j], acc[i][j], 0, 0, 0);
    }
}

// ------------------------------------------------------------ MFMA GEMM bf16
template<bool BIAS, bool RELU, bool OUTBF>
__global__ __launch_bounds__(256)
void gemm_bf(const ushort* __restrict__ A, int lda,
             const ushort* __restrict__ Bt, int ldb,
             const float* __restrict__ bias,
             void* __restrict__ Cp, int ldc,
             int M, int N, int K)
{
    __shared__ __align__(16) ushort sh[17408];   // staging 32KB / epi [128][136]
    ushort* As = sh;
    ushort* Bs = sh + 8192;
    const int t = threadIdx.x;
    const int w = t >> 6, lane = t & 63;
    const int wr = w >> 1, wc = w & 1;
    const int l31 = lane & 31, hi = lane >> 5;
    const int m0 = blockIdx.y * 128, n0 = blockIdx.x * 128;

    const int srow = w * 8 + (lane >> 3);
    const int gchunk = (lane & 7) ^ (srow & 7);
    const ushort* Ag = A + (size_t)(m0 + srow) * lda + gchunk * 8;
    const ushort* Bg = Bt + (size_t)(n0 + srow) * ldb + gchunk * 8;
    ushort* Asw = As + w * 512;
    ushort* Bsw = Bs + w * 512;

    fx16 acc[2][2];
#pragma unroll
    for (int i = 0; i < 2; ++i)
#pragma unroll
        for (int j = 0; j < 2; ++j)
#pragma unroll
            for (int r = 0; r < 16; ++r) acc[i][j][r] = 0.f;

    for (int k0 = 0; k0 < K; k0 += 64) {
#pragma unroll
        for (int c = 0; c < 4; ++c) {
            gload16(Ag + (size_t)c * 32 * lda, Asw + c * 2048);
            gload16(Bg + (size_t)c * 32 * ldb, Bsw + c * 2048);
        }
        Ag += 64; Bg += 64;
        __syncthreads();
        mma32_step(As, Bs, wr * 64, wc * 64, l31, hi, acc);
        __syncthreads();
    }
    const int crow0 = wr * 64, ccol0 = wc * 64;
    if (OUTBF) {
        ushort* Cs = sh;   // [128][136]
#pragma unroll
        for (int i = 0; i < 2; ++i)
#pragma unroll
            for (int j = 0; j < 2; ++j) {
                const int colb = ccol0 + j * 32 + l31;
                float bb = BIAS ? bias[n0 + colb] : 0.f;
                fx16 v = acc[i][j];
#pragma unroll
                for (int r = 0; r < 16; ++r) {
                    float o = v[r] + bb;
                    if (RELU) o = fmaxf(o, 0.f);
                    const int rw = crow0 + i * 32 + (r & 3) + 8 * (r >> 2) + 4 * hi;
                    Cs[rw * 136 + colb] = f2bf(o);
                }
            }
        __syncthreads();
        const int orow = t >> 1, oc0 = (t & 1) * 64;
        ushort* dst = (ushort*)Cp + (size_t)(m0 + orow) * ldc + n0 + oc0;
#pragma unroll
        for (int u = 0; u < 8; ++u)
            *(bf8_t*)(dst + u * 8) = *(const bf8_t*)(Cs + orow * 136 + oc0 + u * 8);
    } else {
        float* C = (float*)Cp;
#pragma unroll
        for (int i = 0; i < 2; ++i)
#pragma unroll
            for (int j = 0; j < 2; ++j) {
                const int colb = n0 + ccol0 + j * 32 + l31;
                float bb = BIAS ? bias[colb] : 0.f;
                fx16 v = acc[i][j];
#pragma unroll
                for (int r = 0; r < 16; ++r) {
                    float o = v[r] + bb;
                    if (RELU) o = fmaxf(o, 0.f);
                    const int rw = crow0 + i * 32 + (r & 3) + 8 * (r >> 2) + 4 * hi;
                    C[(size_t)(m0 + rw) * ldc + colb] = o;
                }
            }
    }
}

// -------------------------------------- batched r = pos_emb @ Wr[l], 4 layers
__global__ __launch_bounds__(256)
void gemm_r4(const ushort* __restrict__ A, const ushort* __restrict__ WrT,
             ushort* __restrict__ R4)
{
    __shared__ __align__(16) ushort sh[17408];
    ushort* As = sh;
    ushort* Bs = sh + 8192;
    const int t = threadIdx.x;
    const int w = t >> 6, lane = t & 63;
    const int wr = w >> 1, wc = w & 1;
    const int l31 = lane & 31, hi = lane >> 5;
    const int m0 = blockIdx.y * 128, n0 = blockIdx.x * 128;
    const ushort* Bt = WrT + (size_t)blockIdx.z * 262144;
    ushort* Cp = R4 + (size_t)blockIdx.z * 262144;

    const int srow = w * 8 + (lane >> 3);
    const int gchunk = (lane & 7) ^ (srow & 7);
    const ushort* Ag = A + (size_t)(m0 + srow) * 512 + gchunk * 8;
    const ushort* Bg = Bt + (size_t)(n0 + srow) * 512 + gchunk * 8;
    ushort* Asw = As + w * 512;
    ushort* Bsw = Bs + w * 512;

    fx16 acc[2][2];
#pragma unroll
    for (int i = 0; i < 2; ++i)
#pragma unroll
        for (int j = 0; j < 2; ++j)
#pragma unroll
            for (int r = 0; r < 16; ++r) acc[i][j][r] = 0.f;

    for (int k0 = 0; k0 < 512; k0 += 64) {
#pragma unroll
        for (int c = 0; c < 4; ++c) {
            gload16(Ag + (size_t)c * 32 * 512, Asw + c * 2048);
            gload16(Bg + (size_t)c * 32 * 512, Bsw + c * 2048);
        }
        Ag += 64; Bg += 64;
        __syncthreads();
        mma32_step(As, Bs, wr * 64, wc * 64, l31, hi, acc);
        __syncthreads();
    }
    const int crow0 = wr * 64, ccol0 = wc * 64;
    ushort* Cs = sh;   // [128][136]
#pragma unroll
    for (int i = 0; i < 2; ++i)
#pragma unroll
        for (int j = 0; j < 2; ++j) {
            const int colb = ccol0 + j * 32 + l31;
            fx16 v = acc[i][j];
#pragma unroll
            for (int r = 0; r < 16; ++r) {
                const int rw = crow0 + i * 32 + (r & 3) + 8 * (r >> 2) + 4 * hi;
                Cs[rw * 136 + colb] = f2bf(v[r]);
            }
        }
    __syncthreads();
    const int orow = t >> 1, oc0 = (t & 1) * 64;
    ushort* dst = Cp + (size_t)(m0 + orow) * 512 + n0 + oc0;
#pragma unroll
    for (int u = 0; u < 8; ++u)
        *(bf8_t*)(dst + u * 8) = *(const bf8_t*)(Cs + orow * 136 + oc0 + u * 8);
}

// ---------------------------------------------- fused q|kv GEMM (col-routed)
__global__ __launch_bounds__(256)
void gemm_qkv(const ushort* __restrict__ A, const ushort* __restrict__ Bt,
              ushort* __restrict__ qout, ushort* __restrict__ kvout)
{
    __shared__ __align__(16) ushort sh[17408];
    ushort* As = sh;
    ushort* Bs = sh + 8192;
    const int t = threadIdx.x;
    const int w = t >> 6, lane = t & 63;
    const int wr = w >> 1, wc = w & 1;
    const int l31 = lane & 31, hi = lane >> 5;
    const int m0 = blockIdx.y * 128, n0 = blockIdx.x * 128;

    const int srow = w * 8 + (lane >> 3);
    const int gchunk = (lane & 7) ^ (srow & 7);
    const ushort* Ag = A + (size_t)(m0 + srow) * 512 + gchunk * 8;
    const ushort* Bg = Bt + (size_t)(n0 + srow) * 512 + gchunk * 8;
    ushort* Asw = As + w * 512;
    ushort* Bsw = Bs + w * 512;

    fx16 acc[2][2];
#pragma unroll
    for (int i = 0; i < 2; ++i)
#pragma unroll
        for (int j = 0; j < 2; ++j)
#pragma unroll
            for (int r = 0; r < 16; ++r) acc[i][j][r] = 0.f;

    for (int k0 = 0; k0 < 512; k0 += 64) {
#pragma unroll
        for (int c = 0; c < 4; ++c) {
            gload16(Ag + (size_t)c * 32 * 512, Asw + c * 2048);
            gload16(Bg + (size_t)c * 32 * 512, Bsw + c * 2048);
        }
        Ag += 64; Bg += 64;
        __syncthreads();
        mma32_step(As, Bs, wr * 64, wc * 64, l31, hi, acc);
        __syncthreads();
    }
    const int crow0 = wr * 64, ccol0 = wc * 64;
    ushort* Cs = sh;   // [128][136]
#pragma unroll
    for (int i = 0; i < 2; ++i)
#pragma unroll
        for (int j = 0; j < 2; ++j) {
            const int colb = ccol0 + j * 32 + l31;
            fx16 v = acc[i][j];
#pragma unroll
            for (int r = 0; r < 16; ++r) {
                const int rw = crow0 + i * 32 + (r & 3) + 8 * (r >> 2) + 4 * hi;
                Cs[rw * 136 + colb] = f2bf(v[r]);
            }
        }
    __syncthreads();
    ushort* base; size_t ldc2;
    if (n0 < 512) { base = qout + n0; ldc2 = 512; }
    else          { base = kvout + (size_t)8192 * 1024 + (n0 - 512); ldc2 = 1024; }
    const int orow = t >> 1, oc0 = (t & 1) * 64;
    ushort* dst = base + (size_t)(m0 + orow) * ldc2 + oc0;
#pragma unroll
    for (int u = 0; u < 8; ++u)
        *(bf8_t*)(dst + u * 8) = *(const bf8_t*)(Cs + orow * 136 + oc0 + u * 8);
}

// ------------------------------------------------ split-K GEMM (f32 partials)
template<bool BIAS>
__global__ __launch_bounds__(256)
void gemm_sk(const ushort* __restrict__ A, int lda,
             const ushort* __restrict__ Bt, int ldb,
             const float* __restrict__ bias,
             float* __restrict__ C0, float* __restrict__ C1, int ldc, int KH)
{
    __shared__ __align__(16) ushort sh[16384];
    ushort* As = sh;
    ushort* Bs = sh + 8192;
    const int t = threadIdx.x;
    const int w = t >> 6, lane = t & 63;
    const int wr = w >> 1, wc = w & 1;
    const int l31 = lane & 31, hi = lane >> 5;
    const int m0 = blockIdx.y * 128, n0 = blockIdx.x * 128;
    const int z = blockIdx.z;
    A += (size_t)z * KH; Bt += (size_t)z * KH;
    float* C = z ? C1 : C0;

    const int srow = w * 8 + (lane >> 3);
    const int gchunk = (lane & 7) ^ (srow & 7);
    const ushort* Ag = A + (size_t)(m0 + srow) * lda + gchunk * 8;
    const ushort* Bg = Bt + (size_t)(n0 + srow) * ldb + gchunk * 8;
    ushort* Asw = As + w * 512;
    ushort* Bsw = Bs + w * 512;

    fx16 acc[2][2];
#pragma unroll
    for (int i = 0; i < 2; ++i)
#pragma unroll
        for (int j = 0; j < 2; ++j)
#pragma unroll
            for (int r = 0; r < 16; ++r) acc[i][j][r] = 0.f;

    for (int k0 = 0; k0 < KH; k0 += 64) {
#pragma unroll
        for (int c = 0; c < 4; ++c) {
            gload16(Ag + (size_t)c * 32 * lda, Asw + c * 2048);
            gload16(Bg + (size_t)c * 32 * ldb, Bsw + c * 2048);
        }
        Ag += 64; Bg += 64;
        __syncthreads();
        mma32_step(As, Bs, wr * 64, wc * 64, l31, hi, acc);
        __syncthreads();
    }
    const int crow0 = wr * 64, ccol0 = wc * 64;
#pragma unroll
    for (int i = 0; i < 2; ++i)
#pragma unroll
        for (int j = 0; j < 2; ++j) {
            const int colb = n0 + ccol0 + j * 32 + l31;
            float bb = (BIAS && z == 0) ? bias[colb] : 0.f;
            fx16 v = acc[i][j];
#pragma unroll
            for (int r = 0; r < 16; ++r) {
                const int rw = crow0 + i * 32 + (r & 3) + 8 * (r >> 2) + 4 * hi;
                C[(size_t)(m0 + rw) * ldc + colb] = v[r] + bb;
            }
        }
}

// ---------------------------------------------------------------- LayerNorm
template<int RMODE, bool TROUT>
__global__ __launch_bounds__(256)
void ln_k(const float* __restrict__ X, const float* __restrict__ X2,
          const void* __restrict__ Rp,
          const float* __restrict__ g, const float* __restrict__ bt,
          float* __restrict__ Yf, ushort* __restrict__ Yb,
          float eps, int do_relu)
{
    const int row  = blockIdx.x * 4 + (threadIdx.x >> 6);
    const int lane = threadIdx.x & 63;
    const float* xp = X + (size_t)row * 512 + lane * 8;
    float4 x0 = *(const float4*)xp, x1 = *(const float4*)(xp + 4);
    float v[8] = {x0.x, x0.y, x0.z, x0.w, x1.x, x1.y, x1.z, x1.w};
    if (RMODE == 3 || RMODE == 4) {
        const float* p2 = X2 + (size_t)row * 512 + lane * 8;
        float4 a0 = *(const float4*)p2, a1 = *(const float4*)(p2 + 4);
        v[0] += a0.x; v[1] += a0.y; v[2] += a0.z; v[3] += a0.w;
        v[4] += a1.x; v[5] += a1.y; v[6] += a1.z; v[7] += a1.w;
    }
    if (RMODE == 1 || RMODE == 4) {
        const float* rp = (const float*)Rp + (size_t)row * 512 + lane * 8;
        float4 r0 = *(const float4*)rp, r1 = *(const float4*)(rp + 4);
        v[0] += r0.x; v[1] += r0.y; v[2] += r0.z; v[3] += r0.w;
        v[4] += r1.x; v[5] += r1.y; v[6] += r1.z; v[7] += r1.w;
    } else if (RMODE == 2 || RMODE == 3) {
        const ushort* rp = (const ushort*)Rp + (size_t)row * 512 + lane * 8;
        ushort4 r0 = *(const ushort4*)rp, r1 = *(const ushort4*)(rp + 4);
        v[0] += b2f(r0.x); v[1] += b2f(r0.y); v[2] += b2f(r0.z); v[3] += b2f(r0.w);
        v[4] += b2f(r1.x); v[5] += b2f(r1.y); v[6] += b2f(r1.z); v[7] += b2f(r1.w);
    }
    float s = 0.f;
#pragma unroll
    for (int i = 0; i < 8; ++i) s += v[i];
#pragma unroll
    for (int m = 1; m < 64; m <<= 1) s += __shfl_xor(s, m);
    float mean = s * (1.f / 512.f);
    float q = 0.f;
#pragma unroll
    for (int i = 0; i < 8; ++i) { float d = v[i] - mean; q = fmaf(d, d, q); }
#pragma unroll
    for (int m = 1; m < 64; m <<= 1) q += __shfl_xor(q, m);
    float rstd = rsqrtf(q * (1.f / 512.f) + eps);
    float4 g0 = *(const float4*)(g + lane * 8), g1 = *(const float4*)(g + lane * 8 + 4);
    float4 c0 = *(const float4*)(bt + lane * 8), c1 = *(const float4*)(bt + lane * 8 + 4);
    float gv[8] = {g0.x, g0.y, g0.z, g0.w, g1.x, g1.y, g1.z, g1.w};
    float bv[8] = {c0.x, c0.y, c0.z, c0.w, c1.x, c1.y, c1.z, c1.w};
    float o[8];
#pragma unroll
    for (int i = 0; i < 8; ++i) {
        o[i] = (v[i] - mean) * rstd * gv[i] + bv[i];
        if (do_relu) o[i] = fmaxf(o[i], 0.f);
    }
    if (Yf) {
        float* yp;
        if (TROUT) {
            const int bq = row & 31, lq = row >> 5;
            yp = Yf + ((size_t)bq * 256 + lq) * 512 + lane * 8;
        } else {
            yp = Yf + (size_t)row * 512 + lane * 8;
        }
        *(float4*)yp       = make_float4(o[0], o[1], o[2], o[3]);
        *(float4*)(yp + 4) = make_float4(o[4], o[5], o[6], o[7]);
    }
    if (Yb) {
        ushort* yp = Yb + (size_t)row * 512 + lane * 8;
        ushort4 w0, w1;
        w0.x = f2bf(o[0]); w0.y = f2bf(o[1]); w0.z = f2bf(o[2]); w0.w = f2bf(o[3]);
        w1.x = f2bf(o[4]); w1.y = f2bf(o[5]); w1.z = f2bf(o[6]); w1.w = f2bf(o[7]);
        *(ushort4*)yp       = w0;
        *(ushort4*)(yp + 4) = w1;
    }
}

// ------------------------------------------ fused stem double LN (ln2 -> lnf)
__global__ __launch_bounds__(256)
void ln_stem2(const float* __restrict__ X,
              const float* __restrict__ g1, const float* __restrict__ b1,
              const float* __restrict__ g2, const float* __restrict__ b2,
              float* __restrict__ Yf, ushort* __restrict__ Yb)
{
    const int row  = blockIdx.x * 4 + (threadIdx.x >> 6);
    const int lane = threadIdx.x & 63;
    const float* xp = X + (size_t)row * 512 + lane * 8;
    float4 x0 = *(const float4*)xp, x1 = *(const float4*)(xp + 4);
    float v[8] = {x0.x, x0.y, x0.z, x0.w, x1.x, x1.y, x1.z, x1.w};
    float s = 0.f;
#pragma unroll
    for (int i = 0; i < 8; ++i) s += v[i];
#pragma unroll
    for (int m = 1; m < 64; m <<= 1) s += __shfl_xor(s, m);
    float mean = s * (1.f / 512.f);
    float q = 0.f;
#pragma unroll
    for (int i = 0; i < 8; ++i) { float d = v[i] - mean; q = fmaf(d, d, q); }
#pragma unroll
    for (int m = 1; m < 64; m <<= 1) q += __shfl_xor(q, m);
    float rstd = rsqrtf(q * (1.f / 512.f) + 1e-5f);
#pragma unroll
    for (int i = 0; i < 8; ++i)
        v[i] = (v[i] - mean) * rstd * g1[lane * 8 + i] + b1[lane * 8 + i];
    s = 0.f;
#pragma unroll
    for (int i = 0; i < 8; ++i) s += v[i];
#pragma unroll
    for (int m = 1; m < 64; m <<= 1) s += __shfl_xor(s, m);
    mean = s * (1.f / 512.f);
    q = 0.f;
#pragma unroll
    for (int i = 0; i < 8; ++i) { float d = v[i] - mean; q = fmaf(d, d, q); }
#pragma unroll
    for (int m = 1; m < 64; m <<= 1) q += __shfl_xor(q, m);
    rstd = rsqrtf(q * (1.f / 512.f) + 1e-6f);
    float o[8];
#pragma unroll
    for (int i = 0; i < 8; ++i)
        o[i] = (v[i] - mean) * rstd * g2[lane * 8 + i] + b2[lane * 8 + i];
    float* yp = Yf + (size_t)row * 512 + lane * 8;
    *(float4*)yp       = make_float4(o[0], o[1], o[2], o[3]);
    *(float4*)(yp + 4) = make_float4(o[4], o[5], o[6], o[7]);
    ushort* yb = Yb + (size_t)row * 512 + lane * 8;
    ushort4 w0, w1;
    w0.x = f2bf(o[0]); w0.y = f2bf(o[1]); w0.z = f2bf(o[2]); w0.w = f2bf(o[3]);
    w1.x = f2bf(o[4]); w1.y = f2bf(o[5]); w1.z = f2bf(o[6]); w1.w = f2bf(o[7]);
    *(ushort4*)yb       = w0;
    *(ushort4*)(yb + 4) = w1;
}

// ---------------------------------------------- weight transpose+cast f32->bf16
__global__ __launch_bounds__(256)
void wtrans(const float* __restrict__ in, ushort* __restrict__ out, int K, int N)
{
    __shared__ float tl[32][33];
    const size_t bo = (size_t)blockIdx.z * K * N;
    in += bo; out += bo;
    const int k0 = blockIdx.y * 32, n0 = blockIdx.x * 32;
    const int tx = threadIdx.x & 31, ty = threadIdx.x >> 5;
    for (int i = ty; i < 32; i += 8) tl[i][tx] = in[(size_t)(k0 + i) * N + n0 + tx];
    __syncthreads();
    for (int i = ty; i < 32; i += 8) out[(size_t)(n0 + i) * K + k0 + tx] = f2bf(tl[tx][i]);
}

__global__ void convk(const float* __restrict__ in, ushort* __restrict__ out)
{
    int i = (blockIdx.x * 256 + threadIdx.x) * 4;
    float4 v = *(const float4*)(in + i);
    ushort4 o;
    o.x = f2bf(v.x); o.y = f2bf(v.y); o.z = f2bf(v.z); o.w = f2bf(v.w);
    *(ushort4*)(out + i) = o;
}

// ----------------------------------------------------- stem concat [x | act]
__global__ void build_xcat(const float* __restrict__ x, const int* __restrict__ action,
                           const float* __restrict__ act_emb, ushort* __restrict__ xcat)
{
    int idx = blockIdx.x * 256 + threadIdx.x;           // 8192*576
    int n = idx / 576, e = idx - n * 576;
    int l = n >> 5, b = n & 31;
    float v;
    if (e < 512) v = x[((size_t)b * 256 + l) * 512 + e];
    else         v = act_emb[action[b * 32 + (l >> 3)] * 64 + (e - 512)];
    xcat[idx] = f2bf(v);
}

// ------------------------------------------------- sinusoidal pos embedding
__global__ void build_posemb(ushort* __restrict__ pe)
{
    int idx = blockIdx.x * 256 + threadIdx.x;           // 512*512
    int j = idx >> 9, c = idx & 511;
    float pf = (float)(511 - j);
    int i2 = (c < 256) ? c : c - 256;
    float inv = expf(-(float)i2 * 0.03597789207803197f);
    float ang = pf * inv;
    pe[idx] = f2bf((c < 256) ? sinf(ang) : cosf(ang));
}

// --------------------------------------------------- MFMA flash attention
// r12 kernel + (a) XCD-aware block remap: b = (p&7)*4 + (p>>7) so each XCD
// owns 4 batches' kv slice (4MB, L2-fit); (b) Vs XOR swizzle: element (d,j)
// at row d, chunk (j>>3)^((d>>3)&7) — makes the 8 scalar V^T writes 2-way
// (was 8-way: 8-row stride x 36-dword pitch ≡ 0 mod 32 banks).
__global__ __launch_bounds__(512)
void attn_mfma(const ushort* __restrict__ q,    // [256*32][512]
               const ushort* __restrict__ kv,   // [512*32][1024]  k | v halves
               const ushort* __restrict__ rb,   // [512][512]
               const float* __restrict__ ub, const float* __restrict__ vb,
               ushort* __restrict__ ao)         // [256*32][512]
{
    __shared__ __align__(16) ushort Ks[64][72];     // K tile  [j][d]
    __shared__ __align__(16) ushort Vs[64][72];     // V^T tile [d][j], XOR-swz
    __shared__ __align__(16) ushort Rs[192][72];    // rolling r band (3 slabs)
    __shared__ __align__(16) ushort Ps[8][16][72];  // per-wave P / O bounce
    const int t = threadIdx.x;
    const int wv = t >> 6, lane = t & 63;
    const int lc = lane & 15, lr = lane >> 4;
    // XCD-aware bijective remap of 512 blocks: [b_hi:2][h,ihalf:4][xcd:3]
    const int p = (int)blockIdx.x;
    const int b = (p & 7) * 4 + (p >> 7);
    const int hi2 = (p >> 3) & 15;
    const int h = hi2 >> 1, ihalf = hi2 & 1;
    const int i0 = ihalf << 7;
    const int iw = i0 + wv * 16;

    // q A-fragments with u/v bias folded
    bf8_t au[2], aw[2];
#pragma unroll
    for (int kk = 0; kk < 2; ++kk) {
        const ushort* qp = q + ((size_t)(iw + lc) * 32 + b) * 512 + h * 64 + kk * 32 + lr * 8;
        bf8_t q8 = *(const bf8_t*)qp;
        const float* up = ub + h * 64 + kk * 32 + lr * 8;
        const float* vp = vb + h * 64 + kk * 32 + lr * 8;
#pragma unroll
        for (int e = 0; e < 8; ++e) {
            float qf = b2f((ushort)q8[e]);
            au[kk][e] = (short)f2bf(qf + up[e]);
            aw[kk][e] = (short)f2bf(qf + vp[e]);
        }
    }

    // staging indices
    const int jl = t >> 3, d0 = (t & 7) * 8;
    const int vrow = ((t >> 3) & 7) * 8 + wv;
    const int vswz = ((((vrow >> 3) ^ (t & 7)) & 7) << 3) + (vrow & 7);  // chunk^=(d>>3)

    f4_t o[4];
#pragma unroll
    for (int d = 0; d < 4; ++d) o[d] = (f4_t){0.f, 0.f, 0.f, 0.f};
    float mrun[4] = {-3.0e38f, -3.0e38f, -3.0e38f, -3.0e38f};
    float lrun[4] = {0.f, 0.f, 0.f, 0.f};

    // ---- prologue: stage tile 0 (K, V^T, all 3 R slabs) ----
    {
        *(bf8_t*)&Ks[jl][d0] = *(const bf8_t*)(kv + ((size_t)jl * 32 + b) * 1024 + h * 64 + d0);
        bf8_t vv = *(const bf8_t*)(kv + ((size_t)vrow * 32 + b) * 1024 + 512 + h * 64 + d0);
#pragma unroll
        for (int e = 0; e < 8; ++e) Vs[d0 + e][vswz] = (ushort)vv[e];
        const int rbase0 = 128 - i0;
#pragma unroll
        for (int p2 = 0; p2 < 3; ++p2) {
            const int jr = min(rbase0 + p2 * 64 + jl, 511);
            *(bf8_t*)&Rs[p2 * 64 + jl][d0] = *(const bf8_t*)(rb + (size_t)jr * 512 + h * 64 + d0);
        }
    }
    __syncthreads();

    const int njt = ihalf ? 8 : 6;
    for (int jt = 0; jt < njt; ++jt) {
        const int j0 = jt << 6;
        // ---- prefetch next tile into registers (overlaps compute below) ----
        bf8_t pk, pv, pr;
        const bool pfq = (jt + 1 < njt);
        if (pfq) {
            const int j0n = j0 + 64;
            pk = *(const bf8_t*)(kv + ((size_t)(j0n + jl) * 32 + b) * 1024 + h * 64 + d0);
            pv = *(const bf8_t*)(kv + ((size_t)(j0n + vrow) * 32 + b) * 1024 + 512 + h * 64 + d0);
            const int jr = min(j0n - i0 + 256 + jl, 511);
            pr = *(const bf8_t*)(rb + (size_t)jr * 512 + h * 64 + d0);
        }
        // ---- compute on tile jt ----
        if (j0 <= iw + 271) {
            f4_t acf[4], bdf[5];
#pragma unroll
            for (int jj = 0; jj < 4; ++jj) acf[jj] = (f4_t){0.f, 0.f, 0.f, 0.f};
#pragma unroll
            for (int fj = 0; fj < 5; ++fj) bdf[fj] = (f4_t){0.f, 0.f, 0.f, 0.f};
            __builtin_amdgcn_s_setprio(1);
#pragma unroll
            for (int jj = 0; jj < 4; ++jj)
#pragma unroll
                for (int kk = 0; kk < 2; ++kk) {
                    bf8_t kf = *(const bf8_t*)&Ks[jj * 16 + lc][kk * 32 + lr * 8];
                    acf[jj] = __builtin_amdgcn_mfma_f32_16x16x32_bf16(au[kk], kf, acf[jj], 0, 0, 0);
                }
            const int rboff = 112 - wv * 16;
#pragma unroll
            for (int fj = 0; fj < 5; ++fj) {
                const int lbase = rboff + fj * 16;
                const int prow = ((jt + (lbase >> 6)) % 3) * 64 + (lbase & 63) + lc;
#pragma unroll
                for (int kk = 0; kk < 2; ++kk) {
                    bf8_t rf = *(const bf8_t*)&Rs[prow][kk * 32 + lr * 8];
                    bdf[fj] = __builtin_amdgcn_mfma_f32_16x16x32_bf16(aw[kk], rf, bdf[fj], 0, 0, 0);
                }
            }
            __builtin_amdgcn_s_setprio(0);
            // ---- rel-shift shuffle + mask + online softmax ----
            float pm[4][4];
            float mt[4] = {-3.0e38f, -3.0e38f, -3.0e38f, -3.0e38f};
            const int jbase = j0 + lc - iw - 256;
#pragma unroll
            for (int rg = 0; rg < 4; ++rg) {
                const int il = lr * 4 + rg;
                const int srcl = (lane & 48) | ((lc + 15 - il) & 15);
                float shf[5];
#pragma unroll
                for (int fj = 0; fj < 5; ++fj) shf[fj] = __shfl(bdf[fj][rg], srcl, 64);
#pragma unroll
                for (int jj = 0; jj < 4; ++jj) {
                    float bd = (lc > il) ? shf[jj + 1] : shf[jj];
                    float s = (acf[jj][rg] + bd) * 0.125f;
                    if (jbase + jj * 16 > il) s = -1e30f;
                    pm[jj][rg] = s;
                    mt[rg] = fmaxf(mt[rg], s);
                }
            }
            float corr[4];
#pragma unroll
            for (int rg = 0; rg < 4; ++rg) {
#pragma unroll
                for (int mm = 1; mm < 16; mm <<= 1)
                    mt[rg] = fmaxf(mt[rg], __shfl_xor(mt[rg], mm, 64));
                float mnew = fmaxf(mrun[rg], mt[rg]);
                corr[rg] = __expf(mrun[rg] - mnew);
                mrun[rg] = mnew;
            }
            float ps4[4] = {0.f, 0.f, 0.f, 0.f};
#pragma unroll
            for (int jj = 0; jj < 4; ++jj)
#pragma unroll
                for (int rg = 0; rg < 4; ++rg) {
                    float pp = __expf(pm[jj][rg] - mrun[rg]);
                    ps4[rg] += pp;
                    Ps[wv][lr * 4 + rg][jj * 16 + lc] = f2bf(pp);
                }
#pragma unroll
            for (int rg = 0; rg < 4; ++rg) {
#pragma unroll
                for (int mm = 1; mm < 16; mm <<= 1)
                    ps4[rg] += __shfl_xor(ps4[rg], mm, 64);
                lrun[rg] = lrun[rg] * corr[rg] + ps4[rg];
            }
            float c0 = __shfl(corr[0], (lc >> 2) << 4, 64);
            float c1 = __shfl(corr[1], (lc >> 2) << 4, 64);
            float c2 = __shfl(corr[2], (lc >> 2) << 4, 64);
            float c3 = __shfl(corr[3], (lc >> 2) << 4, 64);
            float myc = (lc & 2) ? ((lc & 1) ? c3 : c2) : ((lc & 1) ? c1 : c0);
#pragma unroll
            for (int db = 0; db < 4; ++db)
#pragma unroll
                for (int rg = 0; rg < 4; ++rg) o[db][rg] *= myc;
            __builtin_amdgcn_s_setprio(1);
#pragma unroll
            for (int kb = 0; kb < 2; ++kb) {
                bf8_t pf = *(const bf8_t*)&Ps[wv][lc][kb * 32 + lr * 8];
#pragma unroll
                for (int db = 0; db < 4; ++db) {
                    const int vr = db * 16 + lc;
                    bf8_t vf = *(const bf8_t*)&Vs[vr][((kb * 4 + lr) ^ ((vr >> 3) & 7)) * 8];
                    o[db] = __builtin_amdgcn_mfma_f32_16x16x32_bf16(vf, pf, o[db], 0, 0, 0);
                }
            }
            __builtin_amdgcn_s_setprio(0);
        }
        __syncthreads();                 // all waves done reading LDS tile jt
        if (pfq) {                       // write prefetched tile jt+1
            *(bf8_t*)&Ks[jl][d0] = pk;
#pragma unroll
            for (int e = 0; e < 8; ++e) Vs[d0 + e][vswz] = (ushort)pv[e];
            const int phys = (jt % 3) * 64 + jl;     // slab for logical band top
            *(bf8_t*)&Rs[phys][d0] = pr;
        }
        __syncthreads();                 // writes visible before next compute
    }
    // ---- epilogue: scale by 1/l, bounce O^T -> row-major via Ps, store ----
    float i4[4];
#pragma unroll
    for (int rg = 0; rg < 4; ++rg) i4[rg] = 1.f / lrun[rg];
    float s0 = __shfl(i4[0], (lc >> 2) << 4, 64);
    float s1 = __shfl(i4[1], (lc >> 2) << 4, 64);
    float s2 = __shfl(i4[2], (lc >> 2) << 4, 64);
    float s3 = __shfl(i4[3], (lc >> 2) << 4, 64);
    float myi = (lc & 2) ? ((lc & 1) ? s3 : s2) : ((lc & 1) ? s1 : s0);
#pragma unroll
    for (int db = 0; db < 4; ++db)
#pragma unroll
        for (int rg = 0; rg < 4; ++rg)
            Ps[wv][lc][db * 16 + lr * 4 + rg] = f2bf(o[db][rg] * myi);
    const int il2 = lane >> 2, dsg = (lane & 3) << 4;
    bf8_t e0 = *(const bf8_t*)&Ps[wv][il2][dsg];
    bf8_t e1 = *(const bf8_t*)&Ps[wv][il2][dsg + 8];
    ushort* dst = ao + ((size_t)(iw + il2) * 32 + b) * 512 + h * 64 + dsg;
    *(bf8_t*)dst = e0;
    *(bf8_t*)(dst + 8) = e1;
}

// ---------------------------------------------------------------------------
extern "C" void kernel_launch(void* const* d_in, const int* in_sizes, int n_in,
                              void* d_out, int out_size, void* d_ws, size_t ws_size,
                              hipStream_t stream)
{
    const float* x       = (const float*)d_in[0];
    const int*   action  = (const int*)d_in[1];
    const float* mems    = (const float*)d_in[4];
    const float* act_emb = (const float*)d_in[5];
    const float* stem_w1 = (const float*)d_in[6];
    const float* sln1g   = (const float*)d_in[7];
    const float* sln1b   = (const float*)d_in[8];
    const float* stem_w2 = (const float*)d_in[9];
    const float* sln2g   = (const float*)d_in[10];
    const float* sln2b   = (const float*)d_in[11];
    const float* lnfg    = (const float*)d_in[12];
    const float* lnfb    = (const float*)d_in[13];
    const float* ub      = (const float*)d_in[14];
    const float* vb      = (const float*)d_in[15];
    const float* Wqkv    = (const float*)d_in[16];
    const float* Wr      = (const float*)d_in[17];
    const float* Wo      = (const float*)d_in[18];
    const float* ln1g    = (const float*)d_in[19];
    const float* ln1b    = (const float*)d_in[20];
    const float* W1      = (const float*)d_in[21];
    const float* b1      = (const float*)d_in[22];
    const float* W2      = (const float*)d_in[23];
    const float* b2      = (const float*)d_in[24];
    const float* ln2g    = (const float*)d_in[25];
    const float* ln2b    = (const float*)d_in[26];
    float* out = (float*)d_out;

    // ---- workspace layout (bytes), total ~123.8 MB ----
    char* W = (char*)d_ws;
    float*  cur32 = (float*) (W + 0);           // 16 MB residual f32 / FF2 partial
    float*  g32   = (float*) (W + 16777216);    // 16 MB gemm f32 scratch (hosts memsb)
    ushort* curb  = (ushort*)(W + 33554432);    //  8 MB cur bf16
    ushort* h1b   = (ushort*)(W + 41943040);    //  8 MB h1/ao bf16
    ushort* qb    = (ushort*)(W + 50331648);    //  8 MB q bf16 [8192][512]
    ushort* kvb   = (ushort*)(W + 58720256);    // 32 MB kv bf16 [16384][1024]
    ushort* peb   = (ushort*)(W + 92798976);    // 512 KB
    ushort* wts   = (ushort*)(W + 93323264);    // 27 MB transposed bf16 weights
    ushort* rbuf4 = (ushort*)(W + 121700352);   //  2 MB [4][512][512] r per layer
    ushort* xcatb = kvb;                        // stem alias (dead before kv use)
    ushort* ff1b  = kvb;                        // FF1 alias (kv dead post-attn)
    float*  wopart = (float*)kvb;               // Wo split-K partial (post-attn)
    ushort* memsb = (ushort*)g32;               // alias (g32 dead at layer start)
    ushort* w1t    = wts;                       // [512][576]
    ushort* w2t    = wts + 294912;              // [512][512]
    ushort* wqkvT  = wts + 557056;              // [4][1536][512]
    ushort* wrT    = wts + 3702784;             // [4][512][512]
    ushort* woT    = wts + 4751360;             // [4][512][512]
    ushort* w1T    = wts + 5799936;             // [4][2048][512]
    ushort* w2T    = wts + 9994240;             // [4][512][2048]

    dim3 blk(256);
    wtrans<<<dim3(16, 18, 1), blk, 0, stream>>>(stem_w1, w1t, 576, 512);
    wtrans<<<dim3(16, 16, 1), blk, 0, stream>>>(stem_w2, w2t, 512, 512);
    wtrans<<<dim3(48, 16, 4), blk, 0, stream>>>(Wqkv, wqkvT, 512, 1536);
    wtrans<<<dim3(16, 16, 4), blk, 0, stream>>>(Wr, wrT, 512, 512);
    wtrans<<<dim3(16, 16, 4), blk, 0, stream>>>(Wo, woT, 512, 512);
    wtrans<<<dim3(64, 16, 4), blk, 0, stream>>>(W1, w1T, 512, 2048);
    wtrans<<<dim3(16, 64, 4), blk, 0, stream>>>(W2, w2T, 2048, 512);
    build_posemb<<<1024, blk, 0, stream>>>(peb);
    gemm_r4<<<dim3(4, 4, 4), blk, 0, stream>>>(peb, wrT, rbuf4);

    build_xcat<<<18432, blk, 0, stream>>>(x, action, act_emb, xcatb);
    gemm_bf<false, false, false><<<dim3(4, 64), blk, 0, stream>>>(xcatb, 576, w1t, 576, nullptr, g32, 512, 8192, 512, 576);
    ln_k<0, false><<<2048, blk, 0, stream>>>(g32, nullptr, nullptr, sln1g, sln1b, nullptr, curb, 1e-5f, 1);
    gemm_bf<false, false, false><<<dim3(4, 64), blk, 0, stream>>>(curb, 512, w2t, 512, nullptr, g32, 512, 8192, 512, 512);
    ln_stem2<<<2048, blk, 0, stream>>>(g32, sln2g, sln2b, lnfg, lnfb, cur32, curb);

    for (int l = 0; l < 4; ++l) {
        const ushort* wqkvT_l = wqkvT + (size_t)l * 786432;
        convk<<<4096, blk, 0, stream>>>(mems + (size_t)l * 4194304, memsb);
        gemm_qkv<<<dim3(12, 64), blk, 0, stream>>>(curb, wqkvT_l, qb, kvb);
        gemm_bf<false, false, true><<<dim3(8, 64), blk, 0, stream>>>(memsb, 512, wqkvT_l + 262144, 512, nullptr, kvb, 1024, 8192, 1024, 512);
        attn_mfma<<<512, dim3(512), 0, stream>>>(qb, kvb, rbuf4 + (size_t)l * 262144, ub, vb, h1b);
        gemm_sk<false><<<dim3(4, 64, 2), blk, 0, stream>>>(h1b, 512, woT + (size_t)l * 262144, 512, nullptr, g32, wopart, 512, 256);
        ln_k<4, false><<<2048, blk, 0, stream>>>(g32, wopart, cur32, ln1g + l * 512, ln1b + l * 512, nullptr, h1b, 1e-5f, 0);
        gemm_bf<true, true, true><<<dim3(16, 64), blk, 0, stream>>>(h1b, 512, w1T + (size_t)l * 1048576, 512, b1 + l * 2048, ff1b, 2048, 8192, 2048, 512);
        gemm_sk<true><<<dim3(4, 64, 2), blk, 0, stream>>>(ff1b, 2048, w2T + (size_t)l * 1048576, 2048, b2 + l * 512, g32, cur32, 512, 1024);
        if (l == 3)
            ln_k<3, true><<<2048, blk, 0, stream>>>(g32, cur32, h1b, ln2g + l * 512, ln2b + l * 512, out, nullptr, 1e-5f, 0);
        else
            ln_k<3, false><<<2048, blk, 0, stream>>>(g32, cur32, h1b, ln2g + l * 512, ln2b + l * 512, cur32, curb, 1e-5f, 0);
    }
}

// Round 14
// 852.928 us; speedup vs baseline: 1.1257x; 1.0189x over previous
//
#include <hip/hip_runtime.h>

// TransformerXL forward, MI355X. Round 14: T13 defer-max in attn (skip
// O-rescale while tile max within +8 of frozen running max) + bf16 residual
// stream (drop redundant f32 cur32 residual copy; saves 32MB LN traffic per
// layer). Everything else identical to r13 (869 us).
// L=256, KLEN=512, B=32, E=512, H=8, D=64, FF=2048, NL=4.

typedef __attribute__((ext_vector_type(8))) short bf8_t;    // 8 bf16 in 4 VGPRs
typedef __attribute__((ext_vector_type(4))) float f4_t;
typedef __attribute__((ext_vector_type(16))) float fx16;    // 32x32 accum

__device__ __forceinline__ ushort f2bf(float f) {           // RNE f32->bf16
    uint u = __float_as_uint(f);
    u += 0x7FFFu + ((u >> 16) & 1u);
    return (ushort)(u >> 16);
}
__device__ __forceinline__ float b2f(ushort h) {
    return __uint_as_float(((uint)h) << 16);
}
__device__ __forceinline__ void gload16(const void* g, void* l) {
    __builtin_amdgcn_global_load_lds((const __attribute__((address_space(1))) void*)g,
                                     (__attribute__((address_space(3))) void*)l, 16, 0, 0);
}

// ---------------- shared 32x32x16 MFMA core for one BK=64 step -------------
__device__ __forceinline__ void mma32_step(const ushort* __restrict__ As,
                                           const ushort* __restrict__ Bs,
                                           int rowA0, int colB0,
                                           int l31, int hi, fx16 acc[2][2])
{
#pragma unroll
    for (int kk = 0; kk < 4; ++kk) {
        bf8_t av[2], bv[2];
#pragma unroll
        for (int i = 0; i < 2; ++i) {
            const int row = rowA0 + i * 32 + l31;
            const int ch = (kk * 2 + hi) ^ (row & 7);
            av[i] = *(const bf8_t*)(As + row * 64 + ch * 8);
        }
#pragma unroll
        for (int j = 0; j < 2; ++j) {
            const int row = colB0 + j * 32 + l31;
            const int ch = (kk * 2 + hi) ^ (row & 7);
            bv[j] = *(const bf8_t*)(Bs + row * 64 + ch * 8);
        }
#pragma unroll
        for (int i = 0; i < 2; ++i)
#pragma unroll
            for (int j = 0; j < 2; ++j)
                acc[i][j] = __builtin_amdgcn_mfma_f32_32x32x16_bf16(av[i], bv[j], acc[i][j], 0, 0, 0);
    }
}

// ------------------------------------------------------------ MFMA GEMM bf16
template<bool BIAS, bool RELU, bool OUTBF>
__global__ __launch_bounds__(256)
void gemm_bf(const ushort* __restrict__ A, int lda,
             const ushort* __restrict__ Bt, int ldb,
             const float* __restrict__ bias,
             void* __restrict__ Cp, int ldc,
             int M, int N, int K)
{
    __shared__ __align__(16) ushort sh[17408];   // staging 32KB / epi [128][136]
    ushort* As = sh;
    ushort* Bs = sh + 8192;
    const int t = threadIdx.x;
    const int w = t >> 6, lane = t & 63;
    const int wr = w >> 1, wc = w & 1;
    const int l31 = lane & 31, hi = lane >> 5;
    const int m0 = blockIdx.y * 128, n0 = blockIdx.x * 128;

    const int srow = w * 8 + (lane >> 3);
    const int gchunk = (lane & 7) ^ (srow & 7);
    const ushort* Ag = A + (size_t)(m0 + srow) * lda + gchunk * 8;
    const ushort* Bg = Bt + (size_t)(n0 + srow) * ldb + gchunk * 8;
    ushort* Asw = As + w * 512;
    ushort* Bsw = Bs + w * 512;

    fx16 acc[2][2];
#pragma unroll
    for (int i = 0; i < 2; ++i)
#pragma unroll
        for (int j = 0; j < 2; ++j)
#pragma unroll
            for (int r = 0; r < 16; ++r) acc[i][j][r] = 0.f;

    for (int k0 = 0; k0 < K; k0 += 64) {
#pragma unroll
        for (int c = 0; c < 4; ++c) {
            gload16(Ag + (size_t)c * 32 * lda, Asw + c * 2048);
            gload16(Bg + (size_t)c * 32 * ldb, Bsw + c * 2048);
        }
        Ag += 64; Bg += 64;
        __syncthreads();
        mma32_step(As, Bs, wr * 64, wc * 64, l31, hi, acc);
        __syncthreads();
    }
    const int crow0 = wr * 64, ccol0 = wc * 64;
    if (OUTBF) {
        ushort* Cs = sh;   // [128][136]
#pragma unroll
        for (int i = 0; i < 2; ++i)
#pragma unroll
            for (int j = 0; j < 2; ++j) {
                const int colb = ccol0 + j * 32 + l31;
                float bb = BIAS ? bias[n0 + colb] : 0.f;
                fx16 v = acc[i][j];
#pragma unroll
                for (int r = 0; r < 16; ++r) {
                    float o = v[r] + bb;
                    if (RELU) o = fmaxf(o, 0.f);
                    const int rw = crow0 + i * 32 + (r & 3) + 8 * (r >> 2) + 4 * hi;
                    Cs[rw * 136 + colb] = f2bf(o);
                }
            }
        __syncthreads();
        const int orow = t >> 1, oc0 = (t & 1) * 64;
        ushort* dst = (ushort*)Cp + (size_t)(m0 + orow) * ldc + n0 + oc0;
#pragma unroll
        for (int u = 0; u < 8; ++u)
            *(bf8_t*)(dst + u * 8) = *(const bf8_t*)(Cs + orow * 136 + oc0 + u * 8);
    } else {
        float* C = (float*)Cp;
#pragma unroll
        for (int i = 0; i < 2; ++i)
#pragma unroll
            for (int j = 0; j < 2; ++j) {
                const int colb = n0 + ccol0 + j * 32 + l31;
                float bb = BIAS ? bias[colb] : 0.f;
                fx16 v = acc[i][j];
#pragma unroll
                for (int r = 0; r < 16; ++r) {
                    float o = v[r] + bb;
                    if (RELU) o = fmaxf(o, 0.f);
                    const int rw = crow0 + i * 32 + (r & 3) + 8 * (r >> 2) + 4 * hi;
                    C[(size_t)(m0 + rw) * ldc + colb] = o;
                }
            }
    }
}

// -------------------------------------- batched r = pos_emb @ Wr[l], 4 layers
__global__ __launch_bounds__(256)
void gemm_r4(const ushort* __restrict__ A, const ushort* __restrict__ WrT,
             ushort* __restrict__ R4)
{
    __shared__ __align__(16) ushort sh[17408];
    ushort* As = sh;
    ushort* Bs = sh + 8192;
    const int t = threadIdx.x;
    const int w = t >> 6, lane = t & 63;
    const int wr = w >> 1, wc = w & 1;
    const int l31 = lane & 31, hi = lane >> 5;
    const int m0 = blockIdx.y * 128, n0 = blockIdx.x * 128;
    const ushort* Bt = WrT + (size_t)blockIdx.z * 262144;
    ushort* Cp = R4 + (size_t)blockIdx.z * 262144;

    const int srow = w * 8 + (lane >> 3);
    const int gchunk = (lane & 7) ^ (srow & 7);
    const ushort* Ag = A + (size_t)(m0 + srow) * 512 + gchunk * 8;
    const ushort* Bg = Bt + (size_t)(n0 + srow) * 512 + gchunk * 8;
    ushort* Asw = As + w * 512;
    ushort* Bsw = Bs + w * 512;

    fx16 acc[2][2];
#pragma unroll
    for (int i = 0; i < 2; ++i)
#pragma unroll
        for (int j = 0; j < 2; ++j)
#pragma unroll
            for (int r = 0; r < 16; ++r) acc[i][j][r] = 0.f;

    for (int k0 = 0; k0 < 512; k0 += 64) {
#pragma unroll
        for (int c = 0; c < 4; ++c) {
            gload16(Ag + (size_t)c * 32 * 512, Asw + c * 2048);
            gload16(Bg + (size_t)c * 32 * 512, Bsw + c * 2048);
        }
        Ag += 64; Bg += 64;
        __syncthreads();
        mma32_step(As, Bs, wr * 64, wc * 64, l31, hi, acc);
        __syncthreads();
    }
    const int crow0 = wr * 64, ccol0 = wc * 64;
    ushort* Cs = sh;   // [128][136]
#pragma unroll
    for (int i = 0; i < 2; ++i)
#pragma unroll
        for (int j = 0; j < 2; ++j) {
            const int colb = ccol0 + j * 32 + l31;
            fx16 v = acc[i][j];
#pragma unroll
            for (int r = 0; r < 16; ++r) {
                const int rw = crow0 + i * 32 + (r & 3) + 8 * (r >> 2) + 4 * hi;
                Cs[rw * 136 + colb] = f2bf(v[r]);
            }
        }
    __syncthreads();
    const int orow = t >> 1, oc0 = (t & 1) * 64;
    ushort* dst = Cp + (size_t)(m0 + orow) * 512 + n0 + oc0;
#pragma unroll
    for (int u = 0; u < 8; ++u)
        *(bf8_t*)(dst + u * 8) = *(const bf8_t*)(Cs + orow * 136 + oc0 + u * 8);
}

// ---------------------------------------------- fused q|kv GEMM (col-routed)
__global__ __launch_bounds__(256)
void gemm_qkv(const ushort* __restrict__ A, const ushort* __restrict__ Bt,
              ushort* __restrict__ qout, ushort* __restrict__ kvout)
{
    __shared__ __align__(16) ushort sh[17408];
    ushort* As = sh;
    ushort* Bs = sh + 8192;
    const int t = threadIdx.x;
    const int w = t >> 6, lane = t & 63;
    const int wr = w >> 1, wc = w & 1;
    const int l31 = lane & 31, hi = lane >> 5;
    const int m0 = blockIdx.y * 128, n0 = blockIdx.x * 128;

    const int srow = w * 8 + (lane >> 3);
    const int gchunk = (lane & 7) ^ (srow & 7);
    const ushort* Ag = A + (size_t)(m0 + srow) * 512 + gchunk * 8;
    const ushort* Bg = Bt + (size_t)(n0 + srow) * 512 + gchunk * 8;
    ushort* Asw = As + w * 512;
    ushort* Bsw = Bs + w * 512;

    fx16 acc[2][2];
#pragma unroll
    for (int i = 0; i < 2; ++i)
#pragma unroll
        for (int j = 0; j < 2; ++j)
#pragma unroll
            for (int r = 0; r < 16; ++r) acc[i][j][r] = 0.f;

    for (int k0 = 0; k0 < 512; k0 += 64) {
#pragma unroll
        for (int c = 0; c < 4; ++c) {
            gload16(Ag + (size_t)c * 32 * 512, Asw + c * 2048);
            gload16(Bg + (size_t)c * 32 * 512, Bsw + c * 2048);
        }
        Ag += 64; Bg += 64;
        __syncthreads();
        mma32_step(As, Bs, wr * 64, wc * 64, l31, hi, acc);
        __syncthreads();
    }
    const int crow0 = wr * 64, ccol0 = wc * 64;
    ushort* Cs = sh;   // [128][136]
#pragma unroll
    for (int i = 0; i < 2; ++i)
#pragma unroll
        for (int j = 0; j < 2; ++j) {
            const int colb = ccol0 + j * 32 + l31;
            fx16 v = acc[i][j];
#pragma unroll
            for (int r = 0; r < 16; ++r) {
                const int rw = crow0 + i * 32 + (r & 3) + 8 * (r >> 2) + 4 * hi;
                Cs[rw * 136 + colb] = f2bf(v[r]);
            }
        }
    __syncthreads();
    ushort* base; size_t ldc2;
    if (n0 < 512) { base = qout + n0; ldc2 = 512; }
    else          { base = kvout + (size_t)8192 * 1024 + (n0 - 512); ldc2 = 1024; }
    const int orow = t >> 1, oc0 = (t & 1) * 64;
    ushort* dst = base + (size_t)(m0 + orow) * ldc2 + oc0;
#pragma unroll
    for (int u = 0; u < 8; ++u)
        *(bf8_t*)(dst + u * 8) = *(const bf8_t*)(Cs + orow * 136 + oc0 + u * 8);
}

// ------------------------------------------------ split-K GEMM (f32 partials)
template<bool BIAS>
__global__ __launch_bounds__(256)
void gemm_sk(const ushort* __restrict__ A, int lda,
             const ushort* __restrict__ Bt, int ldb,
             const float* __restrict__ bias,
             float* __restrict__ C0, float* __restrict__ C1, int ldc, int KH)
{
    __shared__ __align__(16) ushort sh[16384];
    ushort* As = sh;
    ushort* Bs = sh + 8192;
    const int t = threadIdx.x;
    const int w = t >> 6, lane = t & 63;
    const int wr = w >> 1, wc = w & 1;
    const int l31 = lane & 31, hi = lane >> 5;
    const int m0 = blockIdx.y * 128, n0 = blockIdx.x * 128;
    const int z = blockIdx.z;
    A += (size_t)z * KH; Bt += (size_t)z * KH;
    float* C = z ? C1 : C0;

    const int srow = w * 8 + (lane >> 3);
    const int gchunk = (lane & 7) ^ (srow & 7);
    const ushort* Ag = A + (size_t)(m0 + srow) * lda + gchunk * 8;
    const ushort* Bg = Bt + (size_t)(n0 + srow) * ldb + gchunk * 8;
    ushort* Asw = As + w * 512;
    ushort* Bsw = Bs + w * 512;

    fx16 acc[2][2];
#pragma unroll
    for (int i = 0; i < 2; ++i)
#pragma unroll
        for (int j = 0; j < 2; ++j)
#pragma unroll
            for (int r = 0; r < 16; ++r) acc[i][j][r] = 0.f;

    for (int k0 = 0; k0 < KH; k0 += 64) {
#pragma unroll
        for (int c = 0; c < 4; ++c) {
            gload16(Ag + (size_t)c * 32 * lda, Asw + c * 2048);
            gload16(Bg + (size_t)c * 32 * ldb, Bsw + c * 2048);
        }
        Ag += 64; Bg += 64;
        __syncthreads();
        mma32_step(As, Bs, wr * 64, wc * 64, l31, hi, acc);
        __syncthreads();
    }
    const int crow0 = wr * 64, ccol0 = wc * 64;
#pragma unroll
    for (int i = 0; i < 2; ++i)
#pragma unroll
        for (int j = 0; j < 2; ++j) {
            const int colb = n0 + ccol0 + j * 32 + l31;
            float bb = (BIAS && z == 0) ? bias[colb] : 0.f;
            fx16 v = acc[i][j];
#pragma unroll
            for (int r = 0; r < 16; ++r) {
                const int rw = crow0 + i * 32 + (r & 3) + 8 * (r >> 2) + 4 * hi;
                C[(size_t)(m0 + rw) * ldc + colb] = v[r] + bb;
            }
        }
}

// ---------------------------------------------------------------- LayerNorm
// RMODE: 0 X; 1 X+Rf32; 2 X+Rbf16; 3 X+X2+Rbf16; 4 X+X2+Rf32.
// TROUT: f32 out transposed to [B,L].
template<int RMODE, bool TROUT>
__global__ __launch_bounds__(256)
void ln_k(const float* __restrict__ X, const float* __restrict__ X2,
          const void* __restrict__ Rp,
          const float* __restrict__ g, const float* __restrict__ bt,
          float* __restrict__ Yf, ushort* __restrict__ Yb,
          float eps, int do_relu)
{
    const int row  = blockIdx.x * 4 + (threadIdx.x >> 6);
    const int lane = threadIdx.x & 63;
    const float* xp = X + (size_t)row * 512 + lane * 8;
    float4 x0 = *(const float4*)xp, x1 = *(const float4*)(xp + 4);
    float v[8] = {x0.x, x0.y, x0.z, x0.w, x1.x, x1.y, x1.z, x1.w};
    if (RMODE == 3 || RMODE == 4) {
        const float* p2 = X2 + (size_t)row * 512 + lane * 8;
        float4 a0 = *(const float4*)p2, a1 = *(const float4*)(p2 + 4);
        v[0] += a0.x; v[1] += a0.y; v[2] += a0.z; v[3] += a0.w;
        v[4] += a1.x; v[5] += a1.y; v[6] += a1.z; v[7] += a1.w;
    }
    if (RMODE == 1 || RMODE == 4) {
        const float* rp = (const float*)Rp + (size_t)row * 512 + lane * 8;
        float4 r0 = *(const float4*)rp, r1 = *(const float4*)(rp + 4);
        v[0] += r0.x; v[1] += r0.y; v[2] += r0.z; v[3] += r0.w;
        v[4] += r1.x; v[5] += r1.y; v[6] += r1.z; v[7] += r1.w;
    } else if (RMODE == 2 || RMODE == 3) {
        const ushort* rp = (const ushort*)Rp + (size_t)row * 512 + lane * 8;
        ushort4 r0 = *(const ushort4*)rp, r1 = *(const ushort4*)(rp + 4);
        v[0] += b2f(r0.x); v[1] += b2f(r0.y); v[2] += b2f(r0.z); v[3] += b2f(r0.w);
        v[4] += b2f(r1.x); v[5] += b2f(r1.y); v[6] += b2f(r1.z); v[7] += b2f(r1.w);
    }
    float s = 0.f;
#pragma unroll
    for (int i = 0; i < 8; ++i) s += v[i];
#pragma unroll
    for (int m = 1; m < 64; m <<= 1) s += __shfl_xor(s, m);
    float mean = s * (1.f / 512.f);
    float q = 0.f;
#pragma unroll
    for (int i = 0; i < 8; ++i) { float d = v[i] - mean; q = fmaf(d, d, q); }
#pragma unroll
    for (int m = 1; m < 64; m <<= 1) q += __shfl_xor(q, m);
    float rstd = rsqrtf(q * (1.f / 512.f) + eps);
    float4 g0 = *(const float4*)(g + lane * 8), g1 = *(const float4*)(g + lane * 8 + 4);
    float4 c0 = *(const float4*)(bt + lane * 8), c1 = *(const float4*)(bt + lane * 8 + 4);
    float gv[8] = {g0.x, g0.y, g0.z, g0.w, g1.x, g1.y, g1.z, g1.w};
    float bv[8] = {c0.x, c0.y, c0.z, c0.w, c1.x, c1.y, c1.z, c1.w};
    float o[8];
#pragma unroll
    for (int i = 0; i < 8; ++i) {
        o[i] = (v[i] - mean) * rstd * gv[i] + bv[i];
        if (do_relu) o[i] = fmaxf(o[i], 0.f);
    }
    if (Yf) {
        float* yp;
        if (TROUT) {
            const int bq = row & 31, lq = row >> 5;
            yp = Yf + ((size_t)bq * 256 + lq) * 512 + lane * 8;
        } else {
            yp = Yf + (size_t)row * 512 + lane * 8;
        }
        *(float4*)yp       = make_float4(o[0], o[1], o[2], o[3]);
        *(float4*)(yp + 4) = make_float4(o[4], o[5], o[6], o[7]);
    }
    if (Yb) {
        ushort* yp = Yb + (size_t)row * 512 + lane * 8;
        ushort4 w0, w1;
        w0.x = f2bf(o[0]); w0.y = f2bf(o[1]); w0.z = f2bf(o[2]); w0.w = f2bf(o[3]);
        w1.x = f2bf(o[4]); w1.y = f2bf(o[5]); w1.z = f2bf(o[6]); w1.w = f2bf(o[7]);
        *(ushort4*)yp       = w0;
        *(ushort4*)(yp + 4) = w1;
    }
}

// ------------------------------------------ fused stem double LN (ln2 -> lnf)
__global__ __launch_bounds__(256)
void ln_stem2(const float* __restrict__ X,
              const float* __restrict__ g1, const float* __restrict__ b1,
              const float* __restrict__ g2, const float* __restrict__ b2,
              ushort* __restrict__ Yb)
{
    const int row  = blockIdx.x * 4 + (threadIdx.x >> 6);
    const int lane = threadIdx.x & 63;
    const float* xp = X + (size_t)row * 512 + lane * 8;
    float4 x0 = *(const float4*)xp, x1 = *(const float4*)(xp + 4);
    float v[8] = {x0.x, x0.y, x0.z, x0.w, x1.x, x1.y, x1.z, x1.w};
    float s = 0.f;
#pragma unroll
    for (int i = 0; i < 8; ++i) s += v[i];
#pragma unroll
    for (int m = 1; m < 64; m <<= 1) s += __shfl_xor(s, m);
    float mean = s * (1.f / 512.f);
    float q = 0.f;
#pragma unroll
    for (int i = 0; i < 8; ++i) { float d = v[i] - mean; q = fmaf(d, d, q); }
#pragma unroll
    for (int m = 1; m < 64; m <<= 1) q += __shfl_xor(q, m);
    float rstd = rsqrtf(q * (1.f / 512.f) + 1e-5f);
#pragma unroll
    for (int i = 0; i < 8; ++i)
        v[i] = (v[i] - mean) * rstd * g1[lane * 8 + i] + b1[lane * 8 + i];
    s = 0.f;
#pragma unroll
    for (int i = 0; i < 8; ++i) s += v[i];
#pragma unroll
    for (int m = 1; m < 64; m <<= 1) s += __shfl_xor(s, m);
    mean = s * (1.f / 512.f);
    q = 0.f;
#pragma unroll
    for (int i = 0; i < 8; ++i) { float d = v[i] - mean; q = fmaf(d, d, q); }
#pragma unroll
    for (int m = 1; m < 64; m <<= 1) q += __shfl_xor(q, m);
    rstd = rsqrtf(q * (1.f / 512.f) + 1e-6f);
    float o[8];
#pragma unroll
    for (int i = 0; i < 8; ++i)
        o[i] = (v[i] - mean) * rstd * g2[lane * 8 + i] + b2[lane * 8 + i];
    ushort* yb = Yb + (size_t)row * 512 + lane * 8;
    ushort4 w0, w1;
    w0.x = f2bf(o[0]); w0.y = f2bf(o[1]); w0.z = f2bf(o[2]); w0.w = f2bf(o[3]);
    w1.x = f2bf(o[4]); w1.y = f2bf(o[5]); w1.z = f2bf(o[6]); w1.w = f2bf(o[7]);
    *(ushort4*)yb       = w0;
    *(ushort4*)(yb + 4) = w1;
}

// ---------------------------------------------- weight transpose+cast f32->bf16
__global__ __launch_bounds__(256)
void wtrans(const float* __restrict__ in, ushort* __restrict__ out, int K, int N)
{
    __shared__ float tl[32][33];
    const size_t bo = (size_t)blockIdx.z * K * N;
    in += bo; out += bo;
    const int k0 = blockIdx.y * 32, n0 = blockIdx.x * 32;
    const int tx = threadIdx.x & 31, ty = threadIdx.x >> 5;
    for (int i = ty; i < 32; i += 8) tl[i][tx] = in[(size_t)(k0 + i) * N + n0 + tx];
    __syncthreads();
    for (int i = ty; i < 32; i += 8) out[(size_t)(n0 + i) * K + k0 + tx] = f2bf(tl[tx][i]);
}

__global__ void convk(const float* __restrict__ in, ushort* __restrict__ out)
{
    int i = (blockIdx.x * 256 + threadIdx.x) * 4;
    float4 v = *(const float4*)(in + i);
    ushort4 o;
    o.x = f2bf(v.x); o.y = f2bf(v.y); o.z = f2bf(v.z); o.w = f2bf(v.w);
    *(ushort4*)(out + i) = o;
}

// ----------------------------------------------------- stem concat [x | act]
__global__ void build_xcat(const float* __restrict__ x, const int* __restrict__ action,
                           const float* __restrict__ act_emb, ushort* __restrict__ xcat)
{
    int idx = blockIdx.x * 256 + threadIdx.x;           // 8192*576
    int n = idx / 576, e = idx - n * 576;
    int l = n >> 5, b = n & 31;
    float v;
    if (e < 512) v = x[((size_t)b * 256 + l) * 512 + e];
    else         v = act_emb[action[b * 32 + (l >> 3)] * 64 + (e - 512)];
    xcat[idx] = f2bf(v);
}

// ------------------------------------------------- sinusoidal pos embedding
__global__ void build_posemb(ushort* __restrict__ pe)
{
    int idx = blockIdx.x * 256 + threadIdx.x;           // 512*512
    int j = idx >> 9, c = idx & 511;
    float pf = (float)(511 - j);
    int i2 = (c < 256) ? c : c - 256;
    float inv = expf(-(float)i2 * 0.03597789207803197f);
    float ang = pf * inv;
    pe[idx] = f2bf((c < 256) ? sinf(ang) : cosf(ang));
}

// --------------------------------------------------- MFMA flash attention
// r13 kernel + T13 defer-max: while each tile's max stays within +8 of the
// FROZEN running max (for all rows in the wave), skip the O-rescale and keep
// mrun — drift bounded by e^8, f32 accumulators absorb it.
__global__ __launch_bounds__(512)
void attn_mfma(const ushort* __restrict__ q,    // [256*32][512]
               const ushort* __restrict__ kv,   // [512*32][1024]  k | v halves
               const ushort* __restrict__ rb,   // [512][512]
               const float* __restrict__ ub, const float* __restrict__ vb,
               ushort* __restrict__ ao)         // [256*32][512]
{
    __shared__ __align__(16) ushort Ks[64][72];     // K tile  [j][d]
    __shared__ __align__(16) ushort Vs[64][72];     // V^T tile [d][j], XOR-swz
    __shared__ __align__(16) ushort Rs[192][72];    // rolling r band (3 slabs)
    __shared__ __align__(16) ushort Ps[8][16][72];  // per-wave P / O bounce
    const int t = threadIdx.x;
    const int wv = t >> 6, lane = t & 63;
    const int lc = lane & 15, lr = lane >> 4;
    // XCD-aware bijective remap of 512 blocks: [b_hi:2][h,ihalf:4][xcd:3]
    const int p = (int)blockIdx.x;
    const int b = (p & 7) * 4 + (p >> 7);
    const int hi2 = (p >> 3) & 15;
    const int h = hi2 >> 1, ihalf = hi2 & 1;
    const int i0 = ihalf << 7;
    const int iw = i0 + wv * 16;

    // q A-fragments with u/v bias folded
    bf8_t au[2], aw[2];
#pragma unroll
    for (int kk = 0; kk < 2; ++kk) {
        const ushort* qp = q + ((size_t)(iw + lc) * 32 + b) * 512 + h * 64 + kk * 32 + lr * 8;
        bf8_t q8 = *(const bf8_t*)qp;
        const float* up = ub + h * 64 + kk * 32 + lr * 8;
        const float* vp = vb + h * 64 + kk * 32 + lr * 8;
#pragma unroll
        for (int e = 0; e < 8; ++e) {
            float qf = b2f((ushort)q8[e]);
            au[kk][e] = (short)f2bf(qf + up[e]);
            aw[kk][e] = (short)f2bf(qf + vp[e]);
        }
    }

    // staging indices
    const int jl = t >> 3, d0 = (t & 7) * 8;
    const int vrow = ((t >> 3) & 7) * 8 + wv;
    const int vswz = ((((vrow >> 3) ^ (t & 7)) & 7) << 3) + (vrow & 7);  // chunk^=(d>>3)

    f4_t o[4];
#pragma unroll
    for (int d = 0; d < 4; ++d) o[d] = (f4_t){0.f, 0.f, 0.f, 0.f};
    float mrun[4] = {-3.0e38f, -3.0e38f, -3.0e38f, -3.0e38f};
    float lrun[4] = {0.f, 0.f, 0.f, 0.f};

    // ---- prologue: stage tile 0 (K, V^T, all 3 R slabs) ----
    {
        *(bf8_t*)&Ks[jl][d0] = *(const bf8_t*)(kv + ((size_t)jl * 32 + b) * 1024 + h * 64 + d0);
        bf8_t vv = *(const bf8_t*)(kv + ((size_t)vrow * 32 + b) * 1024 + 512 + h * 64 + d0);
#pragma unroll
        for (int e = 0; e < 8; ++e) Vs[d0 + e][vswz] = (ushort)vv[e];
        const int rbase0 = 128 - i0;
#pragma unroll
        for (int p2 = 0; p2 < 3; ++p2) {
            const int jr = min(rbase0 + p2 * 64 + jl, 511);
            *(bf8_t*)&Rs[p2 * 64 + jl][d0] = *(const bf8_t*)(rb + (size_t)jr * 512 + h * 64 + d0);
        }
    }
    __syncthreads();

    const int njt = ihalf ? 8 : 6;
    for (int jt = 0; jt < njt; ++jt) {
        const int j0 = jt << 6;
        // ---- prefetch next tile into registers (overlaps compute below) ----
        bf8_t pk, pv, pr;
        const bool pfq = (jt + 1 < njt);
        if (pfq) {
            const int j0n = j0 + 64;
            pk = *(const bf8_t*)(kv + ((size_t)(j0n + jl) * 32 + b) * 1024 + h * 64 + d0);
            pv = *(const bf8_t*)(kv + ((size_t)(j0n + vrow) * 32 + b) * 1024 + 512 + h * 64 + d0);
            const int jr = min(j0n - i0 + 256 + jl, 511);
            pr = *(const bf8_t*)(rb + (size_t)jr * 512 + h * 64 + d0);
        }
        // ---- compute on tile jt ----
        if (j0 <= iw + 271) {
            f4_t acf[4], bdf[5];
#pragma unroll
            for (int jj = 0; jj < 4; ++jj) acf[jj] = (f4_t){0.f, 0.f, 0.f, 0.f};
#pragma unroll
            for (int fj = 0; fj < 5; ++fj) bdf[fj] = (f4_t){0.f, 0.f, 0.f, 0.f};
            __builtin_amdgcn_s_setprio(1);
#pragma unroll
            for (int jj = 0; jj < 4; ++jj)
#pragma unroll
                for (int kk = 0; kk < 2; ++kk) {
                    bf8_t kf = *(const bf8_t*)&Ks[jj * 16 + lc][kk * 32 + lr * 8];
                    acf[jj] = __builtin_amdgcn_mfma_f32_16x16x32_bf16(au[kk], kf, acf[jj], 0, 0, 0);
                }
            const int rboff = 112 - wv * 16;
#pragma unroll
            for (int fj = 0; fj < 5; ++fj) {
                const int lbase = rboff + fj * 16;
                const int prow = ((jt + (lbase >> 6)) % 3) * 64 + (lbase & 63) + lc;
#pragma unroll
                for (int kk = 0; kk < 2; ++kk) {
                    bf8_t rf = *(const bf8_t*)&Rs[prow][kk * 32 + lr * 8];
                    bdf[fj] = __builtin_amdgcn_mfma_f32_16x16x32_bf16(aw[kk], rf, bdf[fj], 0, 0, 0);
                }
            }
            __builtin_amdgcn_s_setprio(0);
            // ---- rel-shift shuffle + mask + online softmax (defer-max) ----
            float pm[4][4];
            float mt[4] = {-3.0e38f, -3.0e38f, -3.0e38f, -3.0e38f};
            const int jbase = j0 + lc - iw - 256;
#pragma unroll
            for (int rg = 0; rg < 4; ++rg) {
                const int il = lr * 4 + rg;
                const int srcl = (lane & 48) | ((lc + 15 - il) & 15);
                float shf[5];
#pragma unroll
                for (int fj = 0; fj < 5; ++fj) shf[fj] = __shfl(bdf[fj][rg], srcl, 64);
#pragma unroll
                for (int jj = 0; jj < 4; ++jj) {
                    float bd = (lc > il) ? shf[jj + 1] : shf[jj];
                    float s = (acf[jj][rg] + bd) * 0.125f;
                    if (jbase + jj * 16 > il) s = -1e30f;
                    pm[jj][rg] = s;
                    mt[rg] = fmaxf(mt[rg], s);
                }
            }
#pragma unroll
            for (int rg = 0; rg < 4; ++rg)
#pragma unroll
                for (int mm = 1; mm < 16; mm <<= 1)
                    mt[rg] = fmaxf(mt[rg], __shfl_xor(mt[rg], mm, 64));
            const bool within = (mt[0] <= mrun[0] + 8.f) & (mt[1] <= mrun[1] + 8.f) &
                                (mt[2] <= mrun[2] + 8.f) & (mt[3] <= mrun[3] + 8.f);
            const bool skip_rescale = __all(within);
            float corr[4] = {1.f, 1.f, 1.f, 1.f};
            if (!skip_rescale) {
#pragma unroll
                for (int rg = 0; rg < 4; ++rg) {
                    float mnew = fmaxf(mrun[rg], mt[rg]);
                    corr[rg] = __expf(mrun[rg] - mnew);
                    mrun[rg] = mnew;
                }
            }
            float ps4[4] = {0.f, 0.f, 0.f, 0.f};
#pragma unroll
            for (int jj = 0; jj < 4; ++jj)
#pragma unroll
                for (int rg = 0; rg < 4; ++rg) {
                    float pp = __expf(pm[jj][rg] - mrun[rg]);
                    ps4[rg] += pp;
                    Ps[wv][lr * 4 + rg][jj * 16 + lc] = f2bf(pp);
                }
#pragma unroll
            for (int rg = 0; rg < 4; ++rg) {
#pragma unroll
                for (int mm = 1; mm < 16; mm <<= 1)
                    ps4[rg] += __shfl_xor(ps4[rg], mm, 64);
                lrun[rg] = lrun[rg] * corr[rg] + ps4[rg];
            }
            if (!skip_rescale) {
                float c0 = __shfl(corr[0], (lc >> 2) << 4, 64);
                float c1 = __shfl(corr[1], (lc >> 2) << 4, 64);
                float c2 = __shfl(corr[2], (lc >> 2) << 4, 64);
                float c3 = __shfl(corr[3], (lc >> 2) << 4, 64);
                float myc = (lc & 2) ? ((lc & 1) ? c3 : c2) : ((lc & 1) ? c1 : c0);
#pragma unroll
                for (int db = 0; db < 4; ++db)
#pragma unroll
                    for (int rg = 0; rg < 4; ++rg) o[db][rg] *= myc;
            }
            __builtin_amdgcn_s_setprio(1);
#pragma unroll
            for (int kb = 0; kb < 2; ++kb) {
                bf8_t pf = *(const bf8_t*)&Ps[wv][lc][kb * 32 + lr * 8];
#pragma unroll
                for (int db = 0; db < 4; ++db) {
                    const int vr = db * 16 + lc;
                    bf8_t vf = *(const bf8_t*)&Vs[vr][((kb * 4 + lr) ^ ((vr >> 3) & 7)) * 8];
                    o[db] = __builtin_amdgcn_mfma_f32_16x16x32_bf16(vf, pf, o[db], 0, 0, 0);
                }
            }
            __builtin_amdgcn_s_setprio(0);
        }
        __syncthreads();                 // all waves done reading LDS tile jt
        if (pfq) {                       // write prefetched tile jt+1
            *(bf8_t*)&Ks[jl][d0] = pk;
#pragma unroll
            for (int e = 0; e < 8; ++e) Vs[d0 + e][vswz] = (ushort)pv[e];
            const int phys = (jt % 3) * 64 + jl;     // slab for logical band top
            *(bf8_t*)&Rs[phys][d0] = pr;
        }
        __syncthreads();                 // writes visible before next compute
    }
    // ---- epilogue: scale by 1/l, bounce O^T -> row-major via Ps, store ----
    float i4[4];
#pragma unroll
    for (int rg = 0; rg < 4; ++rg) i4[rg] = 1.f / lrun[rg];
    float s0 = __shfl(i4[0], (lc >> 2) << 4, 64);
    float s1 = __shfl(i4[1], (lc >> 2) << 4, 64);
    float s2 = __shfl(i4[2], (lc >> 2) << 4, 64);
    float s3 = __shfl(i4[3], (lc >> 2) << 4, 64);
    float myi = (lc & 2) ? ((lc & 1) ? s3 : s2) : ((lc & 1) ? s1 : s0);
#pragma unroll
    for (int db = 0; db < 4; ++db)
#pragma unroll
        for (int rg = 0; rg < 4; ++rg)
            Ps[wv][lc][db * 16 + lr * 4 + rg] = f2bf(o[db][rg] * myi);
    const int il2 = lane >> 2, dsg = (lane & 3) << 4;
    bf8_t e0 = *(const bf8_t*)&Ps[wv][il2][dsg];
    bf8_t e1 = *(const bf8_t*)&Ps[wv][il2][dsg + 8];
    ushort* dst = ao + ((size_t)(iw + il2) * 32 + b) * 512 + h * 64 + dsg;
    *(bf8_t*)dst = e0;
    *(bf8_t*)(dst + 8) = e1;
}

// ---------------------------------------------------------------------------
extern "C" void kernel_launch(void* const* d_in, const int* in_sizes, int n_in,
                              void* d_out, int out_size, void* d_ws, size_t ws_size,
                              hipStream_t stream)
{
    const float* x       = (const float*)d_in[0];
    const int*   action  = (const int*)d_in[1];
    const float* mems    = (const float*)d_in[4];
    const float* act_emb = (const float*)d_in[5];
    const float* stem_w1 = (const float*)d_in[6];
    const float* sln1g   = (const float*)d_in[7];
    const float* sln1b   = (const float*)d_in[8];
    const float* stem_w2 = (const float*)d_in[9];
    const float* sln2g   = (const float*)d_in[10];
    const float* sln2b   = (const float*)d_in[11];
    const float* lnfg    = (const float*)d_in[12];
    const float* lnfb    = (const float*)d_in[13];
    const float* ub      = (const float*)d_in[14];
    const float* vb      = (const float*)d_in[15];
    const float* Wqkv    = (const float*)d_in[16];
    const float* Wr      = (const float*)d_in[17];
    const float* Wo      = (const float*)d_in[18];
    const float* ln1g    = (const float*)d_in[19];
    const float* ln1b    = (const float*)d_in[20];
    const float* W1      = (const float*)d_in[21];
    const float* b1      = (const float*)d_in[22];
    const float* W2      = (const float*)d_in[23];
    const float* b2      = (const float*)d_in[24];
    const float* ln2g    = (const float*)d_in[25];
    const float* ln2b    = (const float*)d_in[26];
    float* out = (float*)d_out;

    // ---- workspace layout (bytes), total ~123.8 MB ----
    char* W = (char*)d_ws;
    float*  cur32 = (float*) (W + 0);           // 16 MB FF2 split-K partial scratch
    float*  g32   = (float*) (W + 16777216);    // 16 MB gemm f32 scratch (hosts memsb)
    ushort* curb  = (ushort*)(W + 33554432);    //  8 MB cur bf16 (residual stream)
    ushort* h1b   = (ushort*)(W + 41943040);    //  8 MB h1/ao bf16
    ushort* qb    = (ushort*)(W + 50331648);    //  8 MB q bf16 [8192][512]
    ushort* kvb   = (ushort*)(W + 58720256);    // 32 MB kv bf16 [16384][1024]
    ushort* peb   = (ushort*)(W + 92798976);    // 512 KB
    ushort* wts   = (ushort*)(W + 93323264);    // 27 MB transposed bf16 weights
    ushort* rbuf4 = (ushort*)(W + 121700352);   //  2 MB [4][512][512] r per layer
    ushort* xcatb = kvb;                        // stem alias (dead before kv use)
    ushort* ff1b  = kvb;                        // FF1 alias (kv dead post-attn)
    float*  wopart = (float*)kvb;               // Wo split-K partial (post-attn)
    ushort* memsb = (ushort*)g32;               // alias (g32 dead at layer start)
    ushort* w1t    = wts;                       // [512][576]
    ushort* w2t    = wts + 294912;              // [512][512]
    ushort* wqkvT  = wts + 557056;              // [4][1536][512]
    ushort* wrT    = wts + 3702784;             // [4][512][512]
    ushort* woT    = wts + 4751360;             // [4][512][512]
    ushort* w1T    = wts + 5799936;             // [4][2048][512]
    ushort* w2T    = wts + 9994240;             // [4][512][2048]

    dim3 blk(256);
    wtrans<<<dim3(16, 18, 1), blk, 0, stream>>>(stem_w1, w1t, 576, 512);
    wtrans<<<dim3(16, 16, 1), blk, 0, stream>>>(stem_w2, w2t, 512, 512);
    wtrans<<<dim3(48, 16, 4), blk, 0, stream>>>(Wqkv, wqkvT, 512, 1536);
    wtrans<<<dim3(16, 16, 4), blk, 0, stream>>>(Wr, wrT, 512, 512);
    wtrans<<<dim3(16, 16, 4), blk, 0, stream>>>(Wo, woT, 512, 512);
    wtrans<<<dim3(64, 16, 4), blk, 0, stream>>>(W1, w1T, 512, 2048);
    wtrans<<<dim3(16, 64, 4), blk, 0, stream>>>(W2, w2T, 2048, 512);
    build_posemb<<<1024, blk, 0, stream>>>(peb);
    gemm_r4<<<dim3(4, 4, 4), blk, 0, stream>>>(peb, wrT, rbuf4);

    build_xcat<<<18432, blk, 0, stream>>>(x, action, act_emb, xcatb);
    gemm_bf<false, false, false><<<dim3(4, 64), blk, 0, stream>>>(xcatb, 576, w1t, 576, nullptr, g32, 512, 8192, 512, 576);
    ln_k<0, false><<<2048, blk, 0, stream>>>(g32, nullptr, nullptr, sln1g, sln1b, nullptr, curb, 1e-5f, 1);
    gemm_bf<false, false, false><<<dim3(4, 64), blk, 0, stream>>>(curb, 512, w2t, 512, nullptr, g32, 512, 8192, 512, 512);
    ln_stem2<<<2048, blk, 0, stream>>>(g32, sln2g, sln2b, lnfg, lnfb, curb);

    for (int l = 0; l < 4; ++l) {
        const ushort* wqkvT_l = wqkvT + (size_t)l * 786432;
        convk<<<4096, blk, 0, stream>>>(mems + (size_t)l * 4194304, memsb);
        gemm_qkv<<<dim3(12, 64), blk, 0, stream>>>(curb, wqkvT_l, qb, kvb);
        gemm_bf<false, false, true><<<dim3(8, 64), blk, 0, stream>>>(memsb, 512, wqkvT_l + 262144, 512, nullptr, kvb, 1024, 8192, 1024, 512);
        attn_mfma<<<512, dim3(512), 0, stream>>>(qb, kvb, rbuf4 + (size_t)l * 262144, ub, vb, h1b);
        // Wo split-K: z0 -> g32, z1 -> wopart (kvb region, dead post-attn)
        gemm_sk<false><<<dim3(4, 64, 2), blk, 0, stream>>>(h1b, 512, woT + (size_t)l * 262144, 512, nullptr, g32, wopart, 512, 256);
        // h1 = LN(g32 + wopart + residual curb[bf16])
        ln_k<3, false><<<2048, blk, 0, stream>>>(g32, wopart, curb, ln1g + l * 512, ln1b + l * 512, nullptr, h1b, 1e-5f, 0);
        gemm_bf<true, true, true><<<dim3(16, 64), blk, 0, stream>>>(h1b, 512, w1T + (size_t)l * 1048576, 512, b1 + l * 2048, ff1b, 2048, 8192, 2048, 512);
        // FF2 split-K: z0 -> g32 (+bias), z1 -> cur32 (f32 scratch)
        gemm_sk<true><<<dim3(4, 64, 2), blk, 0, stream>>>(ff1b, 2048, w2T + (size_t)l * 1048576, 2048, b2 + l * 512, g32, cur32, 512, 1024);
        if (l == 3)
            ln_k<3, true><<<2048, blk, 0, stream>>>(g32, cur32, h1b, ln2g + l * 512, ln2b + l * 512, out, nullptr, 1e-5f, 0);
        else
            ln_k<3, false><<<2048, blk, 0, stream>>>(g32, cur32, h1b, ln2g + l * 512, ln2b + l * 512, nullptr, curb, 1e-5f, 0);
    }
}